// Round 5
// baseline (391.988 us; speedup 1.0000x reference)
//
#include <hip/hip_runtime.h>
#include <hip/hip_cooperative_groups.h>
#include <cstdint>
#include <cstddef>

namespace cg = cooperative_groups;

#define SEQ   2048
#define BBAT  2
#define EMBED 512
#define NH    8
#define HD    64
#define NPOS  34

typedef __bf16 bf16;
typedef __bf16 bf16x8 __attribute__((ext_vector_type(8)));
typedef float  f32x4  __attribute__((ext_vector_type(4)));
typedef int    int32x4 __attribute__((ext_vector_type(4)));

// scale = log2(e)/8 : energy=(qk+bias)/8, computed in exp2 domain.
// ESCALE is folded into Qp at the projection epilogue (z==0).
#define ESCALE 0.1803368801111204f

__device__ __forceinline__ f32x4 mfma16(bf16x8 a, bf16x8 b, f32x4 c){
  return __builtin_amdgcn_mfma_f32_16x16x32_bf16(a, b, c, 0, 0, 0);
}

// lgkm-only barrier: does NOT drain vmcnt, so prefetch global loads stay in
// flight across it. sched_barrier(0) pins LDS ops on the correct side.
__device__ __forceinline__ void barrier_lgkm(){
  asm volatile("s_waitcnt lgkmcnt(0)" ::: "memory");
  __builtin_amdgcn_s_barrier();
  __builtin_amdgcn_sched_barrier(0);
}

// ================= FALLBACK KERNELS (verbatim v5, used if coop launch fails) =================

__global__ __launch_bounds__(256) void k_prep(
    const float* __restrict__ Q, const float* __restrict__ K, const float* __restrict__ V,
    const float* __restrict__ Wq, const float* __restrict__ Wk,
    const float* __restrict__ Wv, const float* __restrict__ Wo,
    const float* __restrict__ RE,
    bf16* __restrict__ Qb, bf16* __restrict__ Kb, bf16* __restrict__ Vb,
    bf16* __restrict__ Wall, bf16* __restrict__ Rb)
{
  const int NCONV = 3*524288;
  const int NW = 196608, NO = 262144;
  int i = blockIdx.x*256 + threadIdx.x;
  if (i < NCONV){
    int tsel = i >> 19, j = i & 524287;
    const float* s = tsel==0 ? Q : (tsel==1 ? K : V);
    bf16* d       = tsel==0 ? Qb : (tsel==1 ? Kb : Vb);
    float4 v = ((const float4*)s)[j];
    union { bf16 e[4]; ushort4 u; } pk;
    pk.e[0]=(bf16)v.x; pk.e[1]=(bf16)v.y; pk.e[2]=(bf16)v.z; pk.e[3]=(bf16)v.w;
    ((ushort4*)d)[j] = pk.u;
  } else {
    int j = i - NCONV;
    if (j < NW){
      int w  = j >> 16;
      int r  = j & 65535;
      int np = r >> 7, c4 = (r & 127) << 2;
      const float* W = (w==0) ? Wq : ((w==1) ? Wk : Wv);
      int src = ((np & 63) << 3) + (np >> 6);
      float4 v = *(const float4*)(W + (size_t)src*512 + c4);
      union { bf16 e[4]; ushort4 u; } pk;
      pk.e[0]=(bf16)v.x; pk.e[1]=(bf16)v.y; pk.e[2]=(bf16)v.z; pk.e[3]=(bf16)v.w;
      *(ushort4*)(Wall + (size_t)w*262144 + (size_t)np*512 + c4) = pk.u;
    } else if (j < NW + NO){
      int jj = j - NW;
      int n = jj >> 9, kp = jj & 511;
      int src = ((kp & 63) << 3) + (kp >> 6);
      Wall[(size_t)3*262144 + (size_t)n*512 + kp] = (bf16)Wo[(size_t)n*512 + src];
    } else {
      int jj = j - NW - NO;
      if (jj < 8*48*64){
        int h  = jj / (48*64);
        int r2 = jj - h*(48*64);
        int p  = r2 >> 6, dd = r2 & 63;
        float v = (p < NPOS) ? RE[(size_t)p*512 + dd*8 + h] : 0.f;
        Rb[jj] = (bf16)v;
      }
    }
  }
}

__global__ __launch_bounds__(256,2) void k_gemm_proj(
    const bf16* __restrict__ Qb, const bf16* __restrict__ Kb, const bf16* __restrict__ Vb,
    const bf16* __restrict__ W,  bf16* __restrict__ Qp, bf16* __restrict__ Kp, bf16* __restrict__ Vt)
{
  const bf16* A  = blockIdx.z==0 ? Qb : (blockIdx.z==1 ? Kb : Vb);
  const bf16* Bw = W + (size_t)blockIdx.z*262144;

  __shared__ __align__(16) bf16 As[128][72];
  __shared__ __align__(16) bf16 Bs[64][72];
  const int t = threadIdx.x;
  const int w = t >> 6, lane = t & 63, l15 = lane & 15, quad = lane >> 4;
  const int wm = (w & 1) * 64, wn = (w >> 1) * 32;
  const int m0 = blockIdx.y * 128, n0 = blockIdx.x * 64;

  f32x4 acc[4][2];
  #pragma unroll
  for (int mt=0; mt<4; ++mt)
    #pragma unroll
    for (int nt=0; nt<2; ++nt) acc[mt][nt] = (f32x4){0.f,0.f,0.f,0.f};

  for (int kt = 0; kt < 512; kt += 64){
    #pragma unroll
    for (int i = 0; i < 4; ++i){
      int lin = t + 256*i;
      int r = lin >> 3, c8 = (lin & 7) << 3;
      *(uint4*)&As[r][c8] = *(const uint4*)(A + (size_t)(m0 + r)*512 + kt + c8);
    }
    #pragma unroll
    for (int i = 0; i < 2; ++i){
      int lin = t + 256*i;
      int r = lin >> 3, c8 = (lin & 7) << 3;
      *(uint4*)&Bs[r][c8] = *(const uint4*)(Bw + (size_t)(n0 + r)*512 + kt + c8);
    }
    __syncthreads();
    #pragma unroll
    for (int ks = 0; ks < 2; ++ks){
      bf16x8 am[4], bn[2];
      #pragma unroll
      for (int x=0;x<4;++x) am[x] = *(const bf16x8*)&As[wm + x*16 + l15][ks*32 + quad*8];
      #pragma unroll
      for (int y=0;y<2;++y) bn[y] = *(const bf16x8*)&Bs[wn + y*16 + l15][ks*32 + quad*8];
      #pragma unroll
      for (int mt=0;mt<4;++mt)
        #pragma unroll
        for (int nt=0;nt<2;++nt)
          acc[mt][nt] = mfma16(am[mt], bn[nt], acc[mt][nt]);
    }
    __syncthreads();
  }

  if (blockIdx.z != 2){
    bf16* C = blockIdx.z==0 ? Qp : Kp;
    const float scl = (blockIdx.z==0) ? ESCALE : 1.0f;
    #pragma unroll
    for (int mt=0;mt<4;++mt)
      #pragma unroll
      for (int r=0;r<4;++r){
        int m = m0 + wm + mt*16 + quad*4 + r;
        #pragma unroll
        for (int nt=0;nt<2;++nt)
          C[(size_t)m*512 + n0 + wn + nt*16 + l15] = (bf16)(acc[mt][nt][r] * scl);
      }
  } else {
    bf16 (*VT)[136] = (bf16(*)[136])As;
    #pragma unroll
    for (int mt=0;mt<4;++mt)
      #pragma unroll
      for (int r=0;r<4;++r){
        int m = wm + mt*16 + quad*4 + r;
        #pragma unroll
        for (int nt=0;nt<2;++nt)
          VT[wn + nt*16 + l15][m] = (bf16)acc[mt][nt][r];
      }
    __syncthreads();
    const int h = blockIdx.x, b = m0 >> 11, s0 = m0 & 2047;
    const int n = t >> 2, c0 = (t & 3) * 32;
    bf16* dst = Vt + ((size_t)((b*NH + h)*HD + n))*SEQ + s0 + c0;
    #pragma unroll
    for (int i = 0; i < 4; ++i)
      *(uint4*)(dst + i*8) = *(const uint4*)&VT[n][c0 + i*8];
  }
}

__global__ __launch_bounds__(256,2) void k_gemm_out(
    const bf16* __restrict__ A, const bf16* __restrict__ Bw, float* __restrict__ C)
{
  __shared__ __align__(16) bf16 As[64][72];
  __shared__ __align__(16) bf16 Bs[64][72];
  const int t = threadIdx.x;
  const int w = t >> 6, lane = t & 63, l15 = lane & 15, quad = lane >> 4;
  const int wm = (w & 1) * 32, wn = (w >> 1) * 32;
  const int m0 = blockIdx.y * 64, n0 = blockIdx.x * 64;

  f32x4 acc[2][2];
  #pragma unroll
  for (int mt=0; mt<2; ++mt)
    #pragma unroll
    for (int nt=0; nt<2; ++nt) acc[mt][nt] = (f32x4){0.f,0.f,0.f,0.f};

  for (int kt = 0; kt < 512; kt += 64){
    #pragma unroll
    for (int i = 0; i < 2; ++i){
      int lin = t + 256*i;
      int r = lin >> 3, c8 = (lin & 7) << 3;
      *(uint4*)&As[r][c8] = *(const uint4*)(A  + (size_t)(m0 + r)*512 + kt + c8);
      *(uint4*)&Bs[r][c8] = *(const uint4*)(Bw + (size_t)(n0 + r)*512 + kt + c8);
    }
    __syncthreads();
    #pragma unroll
    for (int ks = 0; ks < 2; ++ks){
      bf16x8 am[2], bn[2];
      #pragma unroll
      for (int x=0;x<2;++x) am[x] = *(const bf16x8*)&As[wm + x*16 + l15][ks*32 + quad*8];
      #pragma unroll
      for (int y=0;y<2;++y) bn[y] = *(const bf16x8*)&Bs[wn + y*16 + l15][ks*32 + quad*8];
      #pragma unroll
      for (int mt=0;mt<2;++mt)
        #pragma unroll
        for (int nt=0;nt<2;++nt)
          acc[mt][nt] = mfma16(am[mt], bn[nt], acc[mt][nt]);
    }
    __syncthreads();
  }
  #pragma unroll
  for (int mt=0;mt<2;++mt)
    #pragma unroll
    for (int r=0;r<4;++r){
      int m = m0 + wm + mt*16 + quad*4 + r;
      #pragma unroll
      for (int nt=0;nt<2;++nt)
        C[(size_t)m*512 + n0 + wn + nt*16 + l15] = acc[mt][nt][r];
    }
}

__global__ __launch_bounds__(256,2) void k_attn(
    const bf16* __restrict__ Qp, const bf16* __restrict__ Kp,
    const bf16* __restrict__ Vt, const bf16* __restrict__ Rb,
    const int* __restrict__ ids, bf16* __restrict__ Out)
{
  __shared__ __align__(16) bf16 Ks[128][72];
  __shared__ __align__(16) bf16 Vs[64][136];
  __shared__ __align__(16) bf16 Ps[64][136];
  __shared__ float lutT[35][65];
  __shared__ float lsum_s[128];

  const int t = threadIdx.x;
  const int b = blockIdx.z, h = blockIdx.y;
  const int q0 = blockIdx.x * 64;
  const int w = t >> 6, lane = t & 63, l15 = lane & 15, quad = lane >> 4;
  const int qh = w & 1, kh = w >> 1;

  const size_t idb = (size_t)b*SEQ*SEQ;
  const bf16* kbase = Kp + (size_t)b*SEQ*EMBED + h*HD;
  const bf16* vbase = Vt + (size_t)(b*NH + h)*HD*SEQ;

  const int krow = t >> 3, kcol = (t & 7) << 3;
  const int vrow = t >> 4, vcol = (t & 15) << 3;

  uint4 ka0, ka1, ka2, ka3, va0, va1, va2, va3;
  uint4 kb0, kb1, kb2, kb3, vb0, vb1, vb2, vb3;
  ka0 = *(const uint4*)(kbase + (size_t)(krow     )*EMBED + kcol);
  ka1 = *(const uint4*)(kbase + (size_t)(krow + 32)*EMBED + kcol);
  ka2 = *(const uint4*)(kbase + (size_t)(krow + 64)*EMBED + kcol);
  ka3 = *(const uint4*)(kbase + (size_t)(krow + 96)*EMBED + kcol);
  va0 = *(const uint4*)(vbase + (size_t)(vrow     )*SEQ + vcol);
  va1 = *(const uint4*)(vbase + (size_t)(vrow + 16)*SEQ + vcol);
  va2 = *(const uint4*)(vbase + (size_t)(vrow + 32)*SEQ + vcol);
  va3 = *(const uint4*)(vbase + (size_t)(vrow + 48)*SEQ + vcol);

  int32x4 nid[2][4];
  #pragma unroll
  for (int mt=0; mt<2; ++mt)
    #pragma unroll
    for (int nt=0; nt<4; ++nt)
      nid[mt][nt] = *(const int32x4*)(ids + idb
          + (size_t)(q0 + qh*32 + mt*16 + l15)*SEQ
          + kh*64 + nt*16 + quad*4);

  {
    const bf16* qbrow = Qp + (size_t)(b*SEQ + q0 + w*16 + l15)*EMBED + h*HD;
    bf16x8 ab0 = *(const bf16x8*)(qbrow + quad*8);
    bf16x8 ab1 = *(const bf16x8*)(qbrow + 32 + quad*8);
    const bf16* rh = Rb + h*3072;
    #pragma unroll
    for (int nt = 0; nt < 3; ++nt){
      bf16x8 r0 = *(const bf16x8*)(rh + (nt*16 + l15)*64 + quad*8);
      bf16x8 r1 = *(const bf16x8*)(rh + (nt*16 + l15)*64 + 32 + quad*8);
      f32x4 c = (f32x4){0.f,0.f,0.f,0.f};
      c = mfma16(ab0, r0, c);
      c = mfma16(ab1, r1, c);
      int p = nt*16 + l15;
      if (p < NPOS){
        #pragma unroll
        for (int r = 0; r < 4; ++r)
          lutT[p][w*16 + quad*4 + r] = (p == 0) ? -1e30f : c[r];
      }
    }
  }

  bf16x8 bq[2][2];
  #pragma unroll
  for (int mt = 0; mt < 2; ++mt){
    const bf16* qrow = Qp + (size_t)(b*SEQ + q0 + qh*32 + mt*16 + l15)*EMBED + h*HD;
    bq[mt][0] = *(const bf16x8*)(qrow + quad*8);
    bq[mt][1] = *(const bf16x8*)(qrow + 32 + quad*8);
  }

  f32x4 acc[2][4];
  #pragma unroll
  for (int mt=0;mt<2;++mt)
    #pragma unroll
    for (int nt=0;nt<4;++nt) acc[mt][nt] = (f32x4){0.f,0.f,0.f,0.f};
  float lsum[2] = {0.f, 0.f};

#define ATTN_BODY(KT, K0,K1,K2,K3, V0,V1,V2,V3, L0,L1,L2,L3, M0,M1,M2,M3)       \
  {                                                                             \
    barrier_lgkm();                                                             \
    *(uint4*)&Ks[krow     ][kcol] = K0;                                         \
    *(uint4*)&Ks[krow + 32][kcol] = K1;                                         \
    *(uint4*)&Ks[krow + 64][kcol] = K2;                                         \
    *(uint4*)&Ks[krow + 96][kcol] = K3;                                         \
    *(uint4*)&Vs[vrow     ][vcol] = V0;                                         \
    *(uint4*)&Vs[vrow + 16][vcol] = V1;                                         \
    *(uint4*)&Vs[vrow + 32][vcol] = V2;                                         \
    *(uint4*)&Vs[vrow + 48][vcol] = V3;                                         \
    if ((KT) < 15){                                                             \
      const bf16* kp2 = kbase + (size_t)(((KT)+1)*128)*EMBED + kcol;            \
      const bf16* vp2 = vbase + ((KT)+1)*128 + vcol;                            \
      L0 = *(const uint4*)(kp2 + (size_t)(krow     )*EMBED);                    \
      L1 = *(const uint4*)(kp2 + (size_t)(krow + 32)*EMBED);                    \
      L2 = *(const uint4*)(kp2 + (size_t)(krow + 64)*EMBED);                    \
      L3 = *(const uint4*)(kp2 + (size_t)(krow + 96)*EMBED);                    \
      M0 = *(const uint4*)(vp2 + (size_t)(vrow     )*SEQ);                      \
      M1 = *(const uint4*)(vp2 + (size_t)(vrow + 16)*SEQ);                      \
      M2 = *(const uint4*)(vp2 + (size_t)(vrow + 32)*SEQ);                      \
      M3 = *(const uint4*)(vp2 + (size_t)(vrow + 48)*SEQ);                      \
    }                                                                           \
    barrier_lgkm();                                                             \
    float wvv[2][4][4];                                                         \
    _Pragma("unroll")                                                           \
    for (int mt = 0; mt < 2; ++mt){                                             \
      const float* lcol = &lutT[0][qh*32 + mt*16 + l15];                        \
      _Pragma("unroll")                                                         \
      for (int nt = 0; nt < 4; ++nt){                                           \
        int32x4 v = nid[mt][nt];                                                \
        wvv[mt][nt][0] = lcol[v[0] * 65];                                       \
        wvv[mt][nt][1] = lcol[v[1] * 65];                                       \
        wvv[mt][nt][2] = lcol[v[2] * 65];                                       \
        wvv[mt][nt][3] = lcol[v[3] * 65];                                       \
      }                                                                         \
    }                                                                           \
    if ((KT) < 15){                                                             \
      _Pragma("unroll")                                                         \
      for (int mt = 0; mt < 2; ++mt)                                            \
        _Pragma("unroll")                                                       \
        for (int nt = 0; nt < 4; ++nt)                                          \
          nid[mt][nt] = *(const int32x4*)(ids + idb                             \
              + (size_t)(q0 + qh*32 + mt*16 + l15)*SEQ                          \
              + (((KT)+1)*128) + kh*64 + nt*16 + quad*4);                       \
    }                                                                           \
    f32x4 sf[2][4];                                                             \
    __builtin_amdgcn_s_setprio(1);                                              \
    _Pragma("unroll")                                                           \
    for (int nt = 0; nt < 4; ++nt){                                             \
      bf16x8 ak0 = *(const bf16x8*)&Ks[kh*64 + nt*16 + l15][quad*8];            \
      bf16x8 ak1 = *(const bf16x8*)&Ks[kh*64 + nt*16 + l15][32 + quad*8];       \
      _Pragma("unroll")                                                         \
      for (int mt = 0; mt < 2; ++mt){                                           \
        f32x4 c = (f32x4){0.f,0.f,0.f,0.f};                                     \
        c = mfma16(ak0, bq[mt][0], c);                                          \
        c = mfma16(ak1, bq[mt][1], c);                                          \
        sf[mt][nt] = c;                                                         \
      }                                                                         \
    }                                                                           \
    __builtin_amdgcn_s_setprio(0);                                              \
    _Pragma("unroll")                                                           \
    for (int mt = 0; mt < 2; ++mt){                                             \
      _Pragma("unroll")                                                         \
      for (int nt = 0; nt < 4; ++nt){                                           \
        union { bf16 e[4]; uint2 u; } pk;                                       \
        float p0 = __builtin_amdgcn_exp2f(sf[mt][nt][0] + wvv[mt][nt][0]);      \
        float p1 = __builtin_amdgcn_exp2f(sf[mt][nt][1] + wvv[mt][nt][1]);      \
        float p2 = __builtin_amdgcn_exp2f(sf[mt][nt][2] + wvv[mt][nt][2]);      \
        float p3 = __builtin_amdgcn_exp2f(sf[mt][nt][3] + wvv[mt][nt][3]);      \
        pk.e[0] = (bf16)p0; pk.e[1] = (bf16)p1;                                 \
        pk.e[2] = (bf16)p2; pk.e[3] = (bf16)p3;                                 \
        lsum[mt] += (p0 + p1) + (p2 + p3);                                      \
        *(uint2*)&Ps[qh*32 + mt*16 + l15][kh*64 + nt*16 + quad*4] = pk.u;       \
      }                                                                         \
    }                                                                           \
    __builtin_amdgcn_s_setprio(1);                                              \
    _Pragma("unroll")                                                           \
    for (int ks = 0; ks < 2; ++ks){                                             \
      bf16x8 ap[2];                                                             \
      _Pragma("unroll")                                                         \
      for (int mt = 0; mt < 2; ++mt)                                            \
        ap[mt] = *(const bf16x8*)&Ps[qh*32 + mt*16 + l15][kh*64 + ks*32 + quad*8]; \
      _Pragma("unroll")                                                         \
      for (int nt = 0; nt < 4; ++nt){                                           \
        bf16x8 bv = *(const bf16x8*)&Vs[nt*16 + l15][kh*64 + ks*32 + quad*8];   \
        _Pragma("unroll")                                                       \
        for (int mt = 0; mt < 2; ++mt)                                          \
          acc[mt][nt] = mfma16(ap[mt], bv, acc[mt][nt]);                        \
      }                                                                         \
    }                                                                           \
    __builtin_amdgcn_s_setprio(0);                                              \
  }

  for (int kt2 = 0; kt2 < 16; kt2 += 2){
    ATTN_BODY(kt2,     ka0,ka1,ka2,ka3, va0,va1,va2,va3, kb0,kb1,kb2,kb3, vb0,vb1,vb2,vb3)
    ATTN_BODY(kt2 + 1, kb0,kb1,kb2,kb3, vb0,vb1,vb2,vb3, ka0,ka1,ka2,ka3, va0,va1,va2,va3)
  }
#undef ATTN_BODY

  __syncthreads();

  #pragma unroll
  for (int mt = 0; mt < 2; ++mt){
    float v = lsum[mt];
    v += __shfl_xor(v, 16);
    v += __shfl_xor(v, 32);
    if (quad == 0) lsum_s[kh*64 + qh*32 + mt*16 + l15] = v;
  }

  float* xch = (float*)&Ps[0][0];
  if (kh == 1){
    #pragma unroll
    for (int mt = 0; mt < 2; ++mt)
      #pragma unroll
      for (int nt = 0; nt < 4; ++nt){
        f32x4 a = acc[mt][nt];
        #pragma unroll
        for (int r = 0; r < 4; ++r)
          xch[(qh*32 + mt*16 + quad*4 + r)*65 + nt*16 + l15] = a[r];
      }
  }
  __syncthreads();

  if (kh == 0){
    #pragma unroll
    for (int mt = 0; mt < 2; ++mt){
      #pragma unroll
      for (int r = 0; r < 4; ++r){
        int ql = qh*32 + mt*16 + quad*4 + r;
        float inv = __builtin_amdgcn_rcpf(lsum_s[ql] + lsum_s[64 + ql]);
        #pragma unroll
        for (int nt = 0; nt < 4; ++nt){
          float o = acc[mt][nt][r] + xch[ql*65 + nt*16 + l15];
          Out[(size_t)(b*SEQ + q0 + ql)*EMBED + h*HD + nt*16 + l15] = (bf16)(o*inv);
        }
      }
    }
  }
}

// ================= FUSED COOPERATIVE MEGA-KERNEL =================
// 4 dependent launches -> 1 cooperative launch + 3 grid syncs. Evidence (R0-R4):
// total == k_attn + 125.5us CONSTANT; other kernels sum to ~15-25us of GPU work
// => ~100us is per-launch boundary overhead. Phase bodies are verbatim v5 with
// (a) LDS overlaid into one 62.9KB blob, (b) flat 512-WG index decode,
// (c) grid-stride for prep(8032) and proj(768). 512 WG = exactly 2 WG/CU at
// 62.9KB LDS -> co-residency guaranteed for cooperative launch.
__global__ __launch_bounds__(256,2) void k_mega(
    const float* Q, const float* K, const float* V,
    const int*   ids,
    const float* Wq, const float* Wk, const float* Wv, const float* Wo,
    const float* RE,
    bf16* Qb, bf16* Kb, bf16* Vb,
    bf16* Wall, bf16* Rb,
    bf16* Qp, bf16* Kp, bf16* Vt,
    bf16* AO, float* out)
{
  __shared__ __align__(16) char smem[62864];
  cg::grid_group grid = cg::this_grid();
  const int t = threadIdx.x;
  const int wg = blockIdx.x;

  // ---------------- phase 0: prep (grid-stride over 8032 virtual blocks) ----------------
  {
    const int NCONV = 3*524288;
    const int NW = 196608, NO = 262144;
    for (int blk = wg; blk < 8032; blk += 512){
      int i = blk*256 + t;
      if (i < NCONV){
        int tsel = i >> 19, j = i & 524287;
        const float* s = tsel==0 ? Q : (tsel==1 ? K : V);
        bf16* d       = tsel==0 ? Qb : (tsel==1 ? Kb : Vb);
        float4 v = ((const float4*)s)[j];
        union { bf16 e[4]; ushort4 u; } pk;
        pk.e[0]=(bf16)v.x; pk.e[1]=(bf16)v.y; pk.e[2]=(bf16)v.z; pk.e[3]=(bf16)v.w;
        ((ushort4*)d)[j] = pk.u;
      } else {
        int j = i - NCONV;
        if (j < NW){
          int w2 = j >> 16;
          int r  = j & 65535;
          int np = r >> 7, c4 = (r & 127) << 2;
          const float* W = (w2==0) ? Wq : ((w2==1) ? Wk : Wv);
          int src = ((np & 63) << 3) + (np >> 6);
          float4 v = *(const float4*)(W + (size_t)src*512 + c4);
          union { bf16 e[4]; ushort4 u; } pk;
          pk.e[0]=(bf16)v.x; pk.e[1]=(bf16)v.y; pk.e[2]=(bf16)v.z; pk.e[3]=(bf16)v.w;
          *(ushort4*)(Wall + (size_t)w2*262144 + (size_t)np*512 + c4) = pk.u;
        } else if (j < NW + NO){
          int jj = j - NW;
          int n = jj >> 9, kp = jj & 511;
          int src = ((kp & 63) << 3) + (kp >> 6);
          Wall[(size_t)3*262144 + (size_t)n*512 + kp] = (bf16)Wo[(size_t)n*512 + src];
        } else {
          int jj = j - NW - NO;
          if (jj < 8*48*64){
            int h2 = jj / (48*64);
            int r2 = jj - h2*(48*64);
            int p  = r2 >> 6, dd = r2 & 63;
            float v = (p < NPOS) ? RE[(size_t)p*512 + dd*8 + h2] : 0.f;
            Rb[jj] = (bf16)v;
          }
        }
      }
    }
  }
  grid.sync();

  // ---------------- phase 1: Q/K/V projections (grid-stride over 768 tiles) ----------------
  {
    bf16 (*As)[72] = (bf16(*)[72])smem;              // 128x72x2 = 18432
    bf16 (*Bs)[72] = (bf16(*)[72])(smem + 18432);    // 64x72x2  =  9216
    const int w = t >> 6, lane = t & 63, l15 = lane & 15, quad = lane >> 4;
    const int wm = (w & 1) * 64, wn = (w >> 1) * 32;

    for (int tile = wg; tile < 768; tile += 512){
      const int z  = tile >> 8;
      const int by = (tile & 255) >> 3, bx = tile & 7;
      const bf16* A  = z==0 ? Qb : (z==1 ? Kb : Vb);
      const bf16* Bw = Wall + (size_t)z*262144;
      const int m0 = by * 128, n0 = bx * 64;

      __syncthreads();   // LDS free from previous tile iteration

      f32x4 acc[4][2];
      #pragma unroll
      for (int mt=0; mt<4; ++mt)
        #pragma unroll
        for (int nt=0; nt<2; ++nt) acc[mt][nt] = (f32x4){0.f,0.f,0.f,0.f};

      for (int kt = 0; kt < 512; kt += 64){
        #pragma unroll
        for (int i = 0; i < 4; ++i){
          int lin = t + 256*i;
          int r = lin >> 3, c8 = (lin & 7) << 3;
          *(uint4*)&As[r][c8] = *(const uint4*)(A + (size_t)(m0 + r)*512 + kt + c8);
        }
        #pragma unroll
        for (int i = 0; i < 2; ++i){
          int lin = t + 256*i;
          int r = lin >> 3, c8 = (lin & 7) << 3;
          *(uint4*)&Bs[r][c8] = *(const uint4*)(Bw + (size_t)(n0 + r)*512 + kt + c8);
        }
        __syncthreads();
        #pragma unroll
        for (int ks = 0; ks < 2; ++ks){
          bf16x8 am[4], bn[2];
          #pragma unroll
          for (int x=0;x<4;++x) am[x] = *(const bf16x8*)&As[wm + x*16 + l15][ks*32 + quad*8];
          #pragma unroll
          for (int y=0;y<2;++y) bn[y] = *(const bf16x8*)&Bs[wn + y*16 + l15][ks*32 + quad*8];
          #pragma unroll
          for (int mt=0;mt<4;++mt)
            #pragma unroll
            for (int nt=0;nt<2;++nt)
              acc[mt][nt] = mfma16(am[mt], bn[nt], acc[mt][nt]);
        }
        __syncthreads();
      }

      if (z != 2){
        bf16* C = z==0 ? Qp : Kp;
        const float scl = (z==0) ? ESCALE : 1.0f;
        #pragma unroll
        for (int mt=0;mt<4;++mt)
          #pragma unroll
          for (int r=0;r<4;++r){
            int m = m0 + wm + mt*16 + quad*4 + r;
            #pragma unroll
            for (int nt=0;nt<2;++nt)
              C[(size_t)m*512 + n0 + wn + nt*16 + l15] = (bf16)(acc[mt][nt][r] * scl);
          }
      } else {
        bf16 (*VT)[136] = (bf16(*)[136])As;   // 64x136x2 = 17408 <= 18432
        #pragma unroll
        for (int mt=0;mt<4;++mt)
          #pragma unroll
          for (int r=0;r<4;++r){
            int m = wm + mt*16 + quad*4 + r;
            #pragma unroll
            for (int nt=0;nt<2;++nt)
              VT[wn + nt*16 + l15][m] = (bf16)acc[mt][nt][r];
          }
        __syncthreads();
        const int h = bx, b = m0 >> 11, s0 = m0 & 2047;
        const int n = t >> 2, c0 = (t & 3) * 32;
        bf16* dst = Vt + ((size_t)((b*NH + h)*HD + n))*SEQ + s0 + c0;
        #pragma unroll
        for (int i = 0; i < 4; ++i)
          *(uint4*)(dst + i*8) = *(const uint4*)&VT[n][c0 + i*8];
      }
    }
  }
  grid.sync();

  // ---------------- phase 2: flash attention (512 WGs exact) ----------------
  {
    bf16 (*Ks)[72]   = (bf16(*)[72])smem;              // 18432
    bf16 (*Vs)[136]  = (bf16(*)[136])(smem + 18432);   // 17408
    bf16 (*Ps)[136]  = (bf16(*)[136])(smem + 35840);   // 17408
    float (*lutT)[65]= (float(*)[65])(smem + 53248);   //  9100
    float *lsum_s    = (float*)(smem + 62348);         //   512

    const int b = wg >> 8, h = (wg >> 5) & 7;
    const int q0 = (wg & 31) * 64;
    const int w = t >> 6, lane = t & 63, l15 = lane & 15, quad = lane >> 4;
    const int qh = w & 1, kh = w >> 1;

    const size_t idb = (size_t)b*SEQ*SEQ;
    const bf16* kbase = Kp + (size_t)b*SEQ*EMBED + h*HD;
    const bf16* vbase = Vt + (size_t)(b*NH + h)*HD*SEQ;

    const int krow = t >> 3, kcol = (t & 7) << 3;
    const int vrow = t >> 4, vcol = (t & 15) << 3;

    uint4 ka0, ka1, ka2, ka3, va0, va1, va2, va3;
    uint4 kb0, kb1, kb2, kb3, vb0, vb1, vb2, vb3;
    ka0 = *(const uint4*)(kbase + (size_t)(krow     )*EMBED + kcol);
    ka1 = *(const uint4*)(kbase + (size_t)(krow + 32)*EMBED + kcol);
    ka2 = *(const uint4*)(kbase + (size_t)(krow + 64)*EMBED + kcol);
    ka3 = *(const uint4*)(kbase + (size_t)(krow + 96)*EMBED + kcol);
    va0 = *(const uint4*)(vbase + (size_t)(vrow     )*SEQ + vcol);
    va1 = *(const uint4*)(vbase + (size_t)(vrow + 16)*SEQ + vcol);
    va2 = *(const uint4*)(vbase + (size_t)(vrow + 32)*SEQ + vcol);
    va3 = *(const uint4*)(vbase + (size_t)(vrow + 48)*SEQ + vcol);

    int32x4 nid[2][4];
    #pragma unroll
    for (int mt=0; mt<2; ++mt)
      #pragma unroll
      for (int nt=0; nt<4; ++nt)
        nid[mt][nt] = *(const int32x4*)(ids + idb
            + (size_t)(q0 + qh*32 + mt*16 + l15)*SEQ
            + kh*64 + nt*16 + quad*4);

    {
      const bf16* qbrow = Qp + (size_t)(b*SEQ + q0 + w*16 + l15)*EMBED + h*HD;
      bf16x8 ab0 = *(const bf16x8*)(qbrow + quad*8);
      bf16x8 ab1 = *(const bf16x8*)(qbrow + 32 + quad*8);
      const bf16* rh = Rb + h*3072;
      #pragma unroll
      for (int nt = 0; nt < 3; ++nt){
        bf16x8 r0 = *(const bf16x8*)(rh + (nt*16 + l15)*64 + quad*8);
        bf16x8 r1 = *(const bf16x8*)(rh + (nt*16 + l15)*64 + 32 + quad*8);
        f32x4 c = (f32x4){0.f,0.f,0.f,0.f};
        c = mfma16(ab0, r0, c);
        c = mfma16(ab1, r1, c);
        int p = nt*16 + l15;
        if (p < NPOS){
          #pragma unroll
          for (int r = 0; r < 4; ++r)
            lutT[p][w*16 + quad*4 + r] = (p == 0) ? -1e30f : c[r];
        }
      }
    }

    bf16x8 bq[2][2];
    #pragma unroll
    for (int mt = 0; mt < 2; ++mt){
      const bf16* qrow = Qp + (size_t)(b*SEQ + q0 + qh*32 + mt*16 + l15)*EMBED + h*HD;
      bq[mt][0] = *(const bf16x8*)(qrow + quad*8);
      bq[mt][1] = *(const bf16x8*)(qrow + 32 + quad*8);
    }

    f32x4 acc[2][4];
    #pragma unroll
    for (int mt=0;mt<2;++mt)
      #pragma unroll
      for (int nt=0;nt<4;++nt) acc[mt][nt] = (f32x4){0.f,0.f,0.f,0.f};
    float lsum[2] = {0.f, 0.f};

#define ATTN_BODY(KT, K0,K1,K2,K3, V0,V1,V2,V3, L0,L1,L2,L3, M0,M1,M2,M3)       \
  {                                                                             \
    barrier_lgkm();                                                             \
    *(uint4*)&Ks[krow     ][kcol] = K0;                                         \
    *(uint4*)&Ks[krow + 32][kcol] = K1;                                         \
    *(uint4*)&Ks[krow + 64][kcol] = K2;                                         \
    *(uint4*)&Ks[krow + 96][kcol] = K3;                                         \
    *(uint4*)&Vs[vrow     ][vcol] = V0;                                         \
    *(uint4*)&Vs[vrow + 16][vcol] = V1;                                         \
    *(uint4*)&Vs[vrow + 32][vcol] = V2;                                         \
    *(uint4*)&Vs[vrow + 48][vcol] = V3;                                         \
    if ((KT) < 15){                                                             \
      const bf16* kp2 = kbase + (size_t)(((KT)+1)*128)*EMBED + kcol;            \
      const bf16* vp2 = vbase + ((KT)+1)*128 + vcol;                            \
      L0 = *(const uint4*)(kp2 + (size_t)(krow     )*EMBED);                    \
      L1 = *(const uint4*)(kp2 + (size_t)(krow + 32)*EMBED);                    \
      L2 = *(const uint4*)(kp2 + (size_t)(krow + 64)*EMBED);                    \
      L3 = *(const uint4*)(kp2 + (size_t)(krow + 96)*EMBED);                    \
      M0 = *(const uint4*)(vp2 + (size_t)(vrow     )*SEQ);                      \
      M1 = *(const uint4*)(vp2 + (size_t)(vrow + 16)*SEQ);                      \
      M2 = *(const uint4*)(vp2 + (size_t)(vrow + 32)*SEQ);                      \
      M3 = *(const uint4*)(vp2 + (size_t)(vrow + 48)*SEQ);                      \
    }                                                                           \
    barrier_lgkm();                                                             \
    float wvv[2][4][4];                                                         \
    _Pragma("unroll")                                                           \
    for (int mt = 0; mt < 2; ++mt){                                             \
      const float* lcol = &lutT[0][qh*32 + mt*16 + l15];                        \
      _Pragma("unroll")                                                         \
      for (int nt = 0; nt < 4; ++nt){                                           \
        int32x4 v = nid[mt][nt];                                                \
        wvv[mt][nt][0] = lcol[v[0] * 65];                                       \
        wvv[mt][nt][1] = lcol[v[1] * 65];                                       \
        wvv[mt][nt][2] = lcol[v[2] * 65];                                       \
        wvv[mt][nt][3] = lcol[v[3] * 65];                                       \
      }                                                                         \
    }                                                                           \
    if ((KT) < 15){                                                             \
      _Pragma("unroll")                                                         \
      for (int mt = 0; mt < 2; ++mt)                                            \
        _Pragma("unroll")                                                       \
        for (int nt = 0; nt < 4; ++nt)                                          \
          nid[mt][nt] = *(const int32x4*)(ids + idb                             \
              + (size_t)(q0 + qh*32 + mt*16 + l15)*SEQ                          \
              + (((KT)+1)*128) + kh*64 + nt*16 + quad*4);                       \
    }                                                                           \
    f32x4 sf[2][4];                                                             \
    __builtin_amdgcn_s_setprio(1);                                              \
    _Pragma("unroll")                                                           \
    for (int nt = 0; nt < 4; ++nt){                                             \
      bf16x8 ak0 = *(const bf16x8*)&Ks[kh*64 + nt*16 + l15][quad*8];            \
      bf16x8 ak1 = *(const bf16x8*)&Ks[kh*64 + nt*16 + l15][32 + quad*8];       \
      _Pragma("unroll")                                                         \
      for (int mt = 0; mt < 2; ++mt){                                           \
        f32x4 c = (f32x4){0.f,0.f,0.f,0.f};                                     \
        c = mfma16(ak0, bq[mt][0], c);                                          \
        c = mfma16(ak1, bq[mt][1], c);                                          \
        sf[mt][nt] = c;                                                         \
      }                                                                         \
    }                                                                           \
    __builtin_amdgcn_s_setprio(0);                                              \
    _Pragma("unroll")                                                           \
    for (int mt = 0; mt < 2; ++mt){                                             \
      _Pragma("unroll")                                                         \
      for (int nt = 0; nt < 4; ++nt){                                           \
        union { bf16 e[4]; uint2 u; } pk;                                       \
        float p0 = __builtin_amdgcn_exp2f(sf[mt][nt][0] + wvv[mt][nt][0]);      \
        float p1 = __builtin_amdgcn_exp2f(sf[mt][nt][1] + wvv[mt][nt][1]);      \
        float p2 = __builtin_amdgcn_exp2f(sf[mt][nt][2] + wvv[mt][nt][2]);      \
        float p3 = __builtin_amdgcn_exp2f(sf[mt][nt][3] + wvv[mt][nt][3]);      \
        pk.e[0] = (bf16)p0; pk.e[1] = (bf16)p1;                                 \
        pk.e[2] = (bf16)p2; pk.e[3] = (bf16)p3;                                 \
        lsum[mt] += (p0 + p1) + (p2 + p3);                                      \
        *(uint2*)&Ps[qh*32 + mt*16 + l15][kh*64 + nt*16 + quad*4] = pk.u;       \
      }                                                                         \
    }                                                                           \
    __builtin_amdgcn_s_setprio(1);                                              \
    _Pragma("unroll")                                                           \
    for (int ks = 0; ks < 2; ++ks){                                             \
      bf16x8 ap[2];                                                             \
      _Pragma("unroll")                                                         \
      for (int mt = 0; mt < 2; ++mt)                                            \
        ap[mt] = *(const bf16x8*)&Ps[qh*32 + mt*16 + l15][kh*64 + ks*32 + quad*8]; \
      _Pragma("unroll")                                                         \
      for (int nt = 0; nt < 4; ++nt){                                           \
        bf16x8 bv = *(const bf16x8*)&Vs[nt*16 + l15][kh*64 + ks*32 + quad*8];   \
        _Pragma("unroll")                                                       \
        for (int mt = 0; mt < 2; ++mt)                                          \
          acc[mt][nt] = mfma16(ap[mt], bv, acc[mt][nt]);                        \
      }                                                                         \
    }                                                                           \
    __builtin_amdgcn_s_setprio(0);                                              \
  }

    for (int kt2 = 0; kt2 < 16; kt2 += 2){
      ATTN_BODY(kt2,     ka0,ka1,ka2,ka3, va0,va1,va2,va3, kb0,kb1,kb2,kb3, vb0,vb1,vb2,vb3)
      ATTN_BODY(kt2 + 1, kb0,kb1,kb2,kb3, vb0,vb1,vb2,vb3, ka0,ka1,ka2,ka3, va0,va1,va2,va3)
    }
#undef ATTN_BODY

    __syncthreads();

    #pragma unroll
    for (int mt = 0; mt < 2; ++mt){
      float v = lsum[mt];
      v += __shfl_xor(v, 16);
      v += __shfl_xor(v, 32);
      if (quad == 0) lsum_s[kh*64 + qh*32 + mt*16 + l15] = v;
    }

    float* xch = (float*)&Ps[0][0];
    if (kh == 1){
      #pragma unroll
      for (int mt = 0; mt < 2; ++mt)
        #pragma unroll
        for (int nt = 0; nt < 4; ++nt){
          f32x4 a = acc[mt][nt];
          #pragma unroll
          for (int r = 0; r < 4; ++r)
            xch[(qh*32 + mt*16 + quad*4 + r)*65 + nt*16 + l15] = a[r];
        }
    }
    __syncthreads();

    if (kh == 0){
      #pragma unroll
      for (int mt = 0; mt < 2; ++mt){
        #pragma unroll
        for (int r = 0; r < 4; ++r){
          int ql = qh*32 + mt*16 + quad*4 + r;
          float inv = __builtin_amdgcn_rcpf(lsum_s[ql] + lsum_s[64 + ql]);
          #pragma unroll
          for (int nt = 0; nt < 4; ++nt){
            float o = acc[mt][nt][r] + xch[ql*65 + nt*16 + l15];
            AO[(size_t)(b*SEQ + q0 + ql)*EMBED + h*HD + nt*16 + l15] = (bf16)(o*inv);
          }
        }
      }
    }
  }
  grid.sync();

  // ---------------- phase 3: output projection (512 WGs exact) ----------------
  {
    bf16 (*As)[72] = (bf16(*)[72])smem;             // 64x72x2 = 9216
    bf16 (*Bs)[72] = (bf16(*)[72])(smem + 9216);    // 64x72x2 = 9216
    const bf16* Bw = Wall + (size_t)3*262144;
    const int w = t >> 6, lane = t & 63, l15 = lane & 15, quad = lane >> 4;
    const int wm = (w & 1) * 32, wn = (w >> 1) * 32;
    const int m0 = (wg >> 3) * 64, n0 = (wg & 7) * 64;

    f32x4 acc[2][2];
    #pragma unroll
    for (int mt=0; mt<2; ++mt)
      #pragma unroll
      for (int nt=0; nt<2; ++nt) acc[mt][nt] = (f32x4){0.f,0.f,0.f,0.f};

    for (int kt = 0; kt < 512; kt += 64){
      #pragma unroll
      for (int i = 0; i < 2; ++i){
        int lin = t + 256*i;
        int r = lin >> 3, c8 = (lin & 7) << 3;
        *(uint4*)&As[r][c8] = *(const uint4*)(AO + (size_t)(m0 + r)*512 + kt + c8);
        *(uint4*)&Bs[r][c8] = *(const uint4*)(Bw + (size_t)(n0 + r)*512 + kt + c8);
      }
      __syncthreads();
      #pragma unroll
      for (int ks = 0; ks < 2; ++ks){
        bf16x8 am[2], bn[2];
        #pragma unroll
        for (int x=0;x<2;++x) am[x] = *(const bf16x8*)&As[wm + x*16 + l15][ks*32 + quad*8];
        #pragma unroll
        for (int y=0;y<2;++y) bn[y] = *(const bf16x8*)&Bs[wn + y*16 + l15][ks*32 + quad*8];
        #pragma unroll
        for (int mt=0;mt<2;++mt)
          #pragma unroll
          for (int nt=0;nt<2;++nt)
            acc[mt][nt] = mfma16(am[mt], bn[nt], acc[mt][nt]);
      }
      __syncthreads();
    }
    #pragma unroll
    for (int mt=0;mt<2;++mt)
      #pragma unroll
      for (int r=0;r<4;++r){
        int m = m0 + wm + mt*16 + quad*4 + r;
        #pragma unroll
        for (int nt=0;nt<2;++nt)
          out[(size_t)m*512 + n0 + wn + nt*16 + l15] = acc[mt][nt][r];
      }
  }
}

// ---------------- launch ----------------
extern "C" void kernel_launch(void* const* d_in, const int* in_sizes, int n_in,
                              void* d_out, int out_size, void* d_ws, size_t ws_size,
                              hipStream_t stream)
{
  (void)in_sizes; (void)n_in; (void)out_size;
  const float* Q  = (const float*)d_in[0];
  const float* K  = (const float*)d_in[1];
  const float* V  = (const float*)d_in[2];
  const int*   ID = (const int*)d_in[3];
  const float* Wq = (const float*)d_in[4];
  const float* Wk = (const float*)d_in[5];
  const float* Wv = (const float*)d_in[6];
  const float* Wo = (const float*)d_in[7];
  const float* RE = (const float*)d_in[8];
  float* out = (float*)d_out;

  const size_t MB = (size_t)1 << 20;
  if (ws_size < 36*MB) return;
  char* ws = (char*)d_ws;
  bf16*  Qb    = (bf16*)(ws + 0*MB);             // dead after proj -> AO overlay
  bf16*  Kb    = (bf16*)(ws + 4*MB);
  bf16*  Vb    = (bf16*)(ws + 8*MB);
  bf16*  Qp    = (bf16*)(ws + 12*MB);
  bf16*  Kp    = (bf16*)(ws + 16*MB);
  bf16*  Vt    = (bf16*)(ws + 20*MB);            // (b,h,d,s) written by proj z==2
  bf16*  Wall  = (bf16*)(ws + 24*MB);            // 2 MB (Wq',Wk',Wv',Wo')
  bf16*  Wop   = Wall + (size_t)3*262144;
  bf16*  Rb    = (bf16*)(ws + 26*MB);            // 48 KB
  bf16*  AO    = (bf16*)(ws + 0*MB);             // overlays Qb

  void* args[] = {
    (void*)&Q, (void*)&K, (void*)&V, (void*)&ID,
    (void*)&Wq, (void*)&Wk, (void*)&Wv, (void*)&Wo, (void*)&RE,
    (void*)&Qb, (void*)&Kb, (void*)&Vb,
    (void*)&Wall, (void*)&Rb,
    (void*)&Qp, (void*)&Kp, (void*)&Vt,
    (void*)&AO, (void*)&out
  };
  hipError_t err = hipLaunchCooperativeKernel((void*)k_mega, dim3(512), dim3(256),
                                              args, 0, stream);
  if (err != hipSuccess){
    // fallback: verified 4-kernel pipeline
    k_prep      <<<dim3(8032),    256, 0, stream>>>(Q, K, V, Wq, Wk, Wv, Wo, RE,
                                                    Qb, Kb, Vb, Wall, Rb);
    k_gemm_proj <<<dim3(8,32,3),  256, 0, stream>>>(Qb, Kb, Vb, Wall, Qp, Kp, Vt);
    k_attn      <<<dim3(32,8,2),  256, 0, stream>>>(Qp, Kp, Vt, Rb, ID, AO);
    k_gemm_out  <<<dim3(8,64),    256, 0, stream>>>(AO, Wop, out);
  }
}

// Round 6
// 201.770 us; speedup vs baseline: 1.9427x; 1.9427x over previous
//
#include <hip/hip_runtime.h>
#include <cstdint>
#include <cstddef>

#define SEQ   2048
#define BBAT  2
#define EMBED 512
#define NH    8
#define HD    64
#define NPOS  34

typedef __bf16 bf16;
typedef __bf16 bf16x8 __attribute__((ext_vector_type(8)));
typedef float  f32x4  __attribute__((ext_vector_type(4)));
typedef int    int32x4 __attribute__((ext_vector_type(4)));

// scale = log2(e)/8 : energy=(qk+bias)/8, computed in exp2 domain.
// ESCALE is folded into Qp at the projection epilogue (z==0).
#define ESCALE 0.1803368801111204f

__device__ __forceinline__ f32x4 mfma16(bf16x8 a, bf16x8 b, f32x4 c){
  return __builtin_amdgcn_mfma_f32_16x16x32_bf16(a, b, c, 0, 0, 0);
}

// lgkm-only barrier: does NOT drain vmcnt, so prefetch global loads stay in
// flight across it. sched_barrier(0) pins LDS ops on the correct side.
__device__ __forceinline__ void barrier_lgkm(){
  asm volatile("s_waitcnt lgkmcnt(0)" ::: "memory");
  __builtin_amdgcn_s_barrier();
  __builtin_amdgcn_sched_barrier(0);
}

// ---------------- kernel 1: fused projections (prep folded in) ----------------
// z in {0,1,2}: 128x64-tile GEMM staging f32 A (Q/K/V) and f32 B (Wq/Wk/Wv,
// row-permuted source index) with in-register bf16 conversion -- replicates
// the old k_prep numerics exactly (f32->bf16 RNE then bf16 MFMA).
// z==0 folds ESCALE into Qp. z==2 writes V transposed (b,h,d,s).
// z==3: tiny side-job, Wo column-permute+convert into Wop (needed 2 launches
// later by k_gemm_out).
__global__ __launch_bounds__(256,2) void k_proj(
    const float* __restrict__ Qf, const float* __restrict__ Kf, const float* __restrict__ Vf,
    const float* __restrict__ Wq, const float* __restrict__ Wk, const float* __restrict__ Wv,
    const float* __restrict__ Wo,
    bf16* __restrict__ Qp, bf16* __restrict__ Kp, bf16* __restrict__ Vt,
    bf16* __restrict__ Wop)
{
  const int z = blockIdx.z;
  const int t = threadIdx.x;

  if (z == 3){
    // Wop[n][kp] = (bf16)Wo[n][perm(kp)], perm(kp) = ((kp&63)<<3) + (kp>>6)
    int base = (blockIdx.y*8 + blockIdx.x)*1024 + t*4;
    int n = base >> 9, kp = base & 511;
    union { bf16 e[4]; ushort4 u; } pk;
    #pragma unroll
    for (int j = 0; j < 4; ++j){
      int kpj = kp + j;
      int src = ((kpj & 63) << 3) + (kpj >> 6);
      pk.e[j] = (bf16)Wo[(size_t)n*512 + src];
    }
    *(ushort4*)(Wop + (size_t)n*512 + kp) = pk.u;
    return;
  }

  const float* A  = z==0 ? Qf : (z==1 ? Kf : Vf);
  const float* Bw = z==0 ? Wq : (z==1 ? Wk : Wv);

  __shared__ __align__(16) bf16 As[128][72];
  __shared__ __align__(16) bf16 Bs[64][72];
  const int w = t >> 6, lane = t & 63, l15 = lane & 15, quad = lane >> 4;
  const int wm = (w & 1) * 64, wn = (w >> 1) * 32;
  const int m0 = blockIdx.y * 128, n0 = blockIdx.x * 64;

  f32x4 acc[4][2];
  #pragma unroll
  for (int mt=0; mt<4; ++mt)
    #pragma unroll
    for (int nt=0; nt<2; ++nt) acc[mt][nt] = (f32x4){0.f,0.f,0.f,0.f};

  for (int kt = 0; kt < 512; kt += 64){
    #pragma unroll
    for (int i = 0; i < 4; ++i){
      int lin = t + 256*i;
      int r = lin >> 3, c8 = (lin & 7) << 3;
      const float* src = A + (size_t)(m0 + r)*512 + kt + c8;
      float4 f0 = *(const float4*)(src);
      float4 f1 = *(const float4*)(src + 4);
      union { bf16 e[8]; uint4 u; } pk;
      pk.e[0]=(bf16)f0.x; pk.e[1]=(bf16)f0.y; pk.e[2]=(bf16)f0.z; pk.e[3]=(bf16)f0.w;
      pk.e[4]=(bf16)f1.x; pk.e[5]=(bf16)f1.y; pk.e[6]=(bf16)f1.z; pk.e[7]=(bf16)f1.w;
      *(uint4*)&As[r][c8] = pk.u;
    }
    #pragma unroll
    for (int i = 0; i < 2; ++i){
      int lin = t + 256*i;
      int r = lin >> 3, c8 = (lin & 7) << 3;
      int np = n0 + r;
      int srcrow = ((np & 63) << 3) + (np >> 6);
      const float* src = Bw + (size_t)srcrow*512 + kt + c8;
      float4 f0 = *(const float4*)(src);
      float4 f1 = *(const float4*)(src + 4);
      union { bf16 e[8]; uint4 u; } pk;
      pk.e[0]=(bf16)f0.x; pk.e[1]=(bf16)f0.y; pk.e[2]=(bf16)f0.z; pk.e[3]=(bf16)f0.w;
      pk.e[4]=(bf16)f1.x; pk.e[5]=(bf16)f1.y; pk.e[6]=(bf16)f1.z; pk.e[7]=(bf16)f1.w;
      *(uint4*)&Bs[r][c8] = pk.u;
    }
    __syncthreads();
    #pragma unroll
    for (int ks = 0; ks < 2; ++ks){
      bf16x8 am[4], bn[2];
      #pragma unroll
      for (int x=0;x<4;++x) am[x] = *(const bf16x8*)&As[wm + x*16 + l15][ks*32 + quad*8];
      #pragma unroll
      for (int y=0;y<2;++y) bn[y] = *(const bf16x8*)&Bs[wn + y*16 + l15][ks*32 + quad*8];
      #pragma unroll
      for (int mt=0;mt<4;++mt)
        #pragma unroll
        for (int nt=0;nt<2;++nt)
          acc[mt][nt] = mfma16(am[mt], bn[nt], acc[mt][nt]);
    }
    __syncthreads();
  }

  if (z != 2){
    bf16* C = z==0 ? Qp : Kp;
    const float scl = (z==0) ? ESCALE : 1.0f;
    #pragma unroll
    for (int mt=0;mt<4;++mt)
      #pragma unroll
      for (int r=0;r<4;++r){
        int m = m0 + wm + mt*16 + quad*4 + r;
        #pragma unroll
        for (int nt=0;nt<2;++nt)
          C[(size_t)m*512 + n0 + wn + nt*16 + l15] = (bf16)(acc[mt][nt][r] * scl);
      }
  } else {
    bf16 (*VT)[136] = (bf16(*)[136])As;    // 64x136x2 = 17408 <= 18432
    #pragma unroll
    for (int mt=0;mt<4;++mt)
      #pragma unroll
      for (int r=0;r<4;++r){
        int m = wm + mt*16 + quad*4 + r;
        #pragma unroll
        for (int nt=0;nt<2;++nt)
          VT[wn + nt*16 + l15][m] = (bf16)acc[mt][nt][r];
      }
    __syncthreads();
    const int h = blockIdx.x, b = m0 >> 11, s0 = m0 & 2047;
    const int n = t >> 2, c0 = (t & 3) * 32;
    bf16* dst = Vt + ((size_t)((b*NH + h)*HD + n))*SEQ + s0 + c0;
    #pragma unroll
    for (int i = 0; i < 4; ++i)
      *(uint4*)(dst + i*8) = *(const uint4*)&VT[n][c0 + i*8];
  }
}

// ---------------- kernel 3: output projection, 128x64 tile, f32 out ----------------
__global__ __launch_bounds__(256,2) void k_gemm_out(
    const bf16* __restrict__ A, const bf16* __restrict__ Bw, float* __restrict__ C)
{
  __shared__ __align__(16) bf16 As[128][72];
  __shared__ __align__(16) bf16 Bs[64][72];
  const int t = threadIdx.x;
  const int w = t >> 6, lane = t & 63, l15 = lane & 15, quad = lane >> 4;
  const int wm = (w & 1) * 64, wn = (w >> 1) * 32;
  const int m0 = blockIdx.y * 128, n0 = blockIdx.x * 64;

  f32x4 acc[4][2];
  #pragma unroll
  for (int mt=0; mt<4; ++mt)
    #pragma unroll
    for (int nt=0; nt<2; ++nt) acc[mt][nt] = (f32x4){0.f,0.f,0.f,0.f};

  for (int kt = 0; kt < 512; kt += 64){
    #pragma unroll
    for (int i = 0; i < 4; ++i){
      int lin = t + 256*i;
      int r = lin >> 3, c8 = (lin & 7) << 3;
      *(uint4*)&As[r][c8] = *(const uint4*)(A + (size_t)(m0 + r)*512 + kt + c8);
    }
    #pragma unroll
    for (int i = 0; i < 2; ++i){
      int lin = t + 256*i;
      int r = lin >> 3, c8 = (lin & 7) << 3;
      *(uint4*)&Bs[r][c8] = *(const uint4*)(Bw + (size_t)(n0 + r)*512 + kt + c8);
    }
    __syncthreads();
    #pragma unroll
    for (int ks = 0; ks < 2; ++ks){
      bf16x8 am[4], bn[2];
      #pragma unroll
      for (int x=0;x<4;++x) am[x] = *(const bf16x8*)&As[wm + x*16 + l15][ks*32 + quad*8];
      #pragma unroll
      for (int y=0;y<2;++y) bn[y] = *(const bf16x8*)&Bs[wn + y*16 + l15][ks*32 + quad*8];
      #pragma unroll
      for (int mt=0;mt<4;++mt)
        #pragma unroll
        for (int nt=0;nt<2;++nt)
          acc[mt][nt] = mfma16(am[mt], bn[nt], acc[mt][nt]);
    }
    __syncthreads();
  }
  #pragma unroll
  for (int mt=0;mt<4;++mt)
    #pragma unroll
    for (int r=0;r<4;++r){
      int m = m0 + wm + mt*16 + quad*4 + r;
      #pragma unroll
      for (int nt=0;nt<2;++nt)
        C[(size_t)m*512 + n0 + wn + nt*16 + l15] = acc[mt][nt][r];
    }
}

// ---------------- kernel 2: flash attention (v5 structure, RE read direct) ----------------
// Identical to the verified 58.9us v5 except the LUT build reads f32 RE with
// the stride-8 per-head gather (rel_emb[p][d*8+h]) instead of prestaged Rb.
// OOB rows p>=NPOS: pointer clamped to row 0 and value multiplied by 0.
__global__ __launch_bounds__(256,2) void k_attn(
    const bf16* __restrict__ Qp, const bf16* __restrict__ Kp,
    const bf16* __restrict__ Vt, const float* __restrict__ RE,
    const int* __restrict__ ids, bf16* __restrict__ Out)
{
  // LDS: 18432 + 17408 + 17408 + 9100 + 512 = 62860 B -> 2 WG/CU
  __shared__ __align__(16) bf16 Ks[128][72];
  __shared__ __align__(16) bf16 Vs[64][136];
  __shared__ __align__(16) bf16 Ps[64][136];
  __shared__ float lutT[35][65];
  __shared__ float lsum_s[128];

  const int t = threadIdx.x;
  const int b = blockIdx.z, h = blockIdx.y;
  const int q0 = blockIdx.x * 64;
  const int w = t >> 6, lane = t & 63, l15 = lane & 15, quad = lane >> 4;
  const int qh = w & 1, kh = w >> 1;

  const size_t idb = (size_t)b*SEQ*SEQ;
  const bf16* kbase = Kp + (size_t)b*SEQ*EMBED + h*HD;
  const bf16* vbase = Vt + (size_t)(b*NH + h)*HD*SEQ;

  const int krow = t >> 3, kcol = (t & 7) << 3;
  const int vrow = t >> 4, vcol = (t & 15) << 3;

  // ---- issue tile-0 K/V loads -> named reg set A (fly under LUT build) ----
  uint4 ka0, ka1, ka2, ka3, va0, va1, va2, va3;
  uint4 kb0, kb1, kb2, kb3, vb0, vb1, vb2, vb3;
  ka0 = *(const uint4*)(kbase + (size_t)(krow     )*EMBED + kcol);
  ka1 = *(const uint4*)(kbase + (size_t)(krow + 32)*EMBED + kcol);
  ka2 = *(const uint4*)(kbase + (size_t)(krow + 64)*EMBED + kcol);
  ka3 = *(const uint4*)(kbase + (size_t)(krow + 96)*EMBED + kcol);
  va0 = *(const uint4*)(vbase + (size_t)(vrow     )*SEQ + vcol);
  va1 = *(const uint4*)(vbase + (size_t)(vrow + 16)*SEQ + vcol);
  va2 = *(const uint4*)(vbase + (size_t)(vrow + 32)*SEQ + vcol);
  va3 = *(const uint4*)(vbase + (size_t)(vrow + 48)*SEQ + vcol);

  // ---- prefetch tile-0 ids as int4 ----
  int32x4 nid[2][4];
  #pragma unroll
  for (int mt=0; mt<2; ++mt)
    #pragma unroll
    for (int nt=0; nt<4; ++nt)
      nid[mt][nt] = *(const int32x4*)(ids + idb
          + (size_t)(q0 + qh*32 + mt*16 + l15)*SEQ
          + kh*64 + nt*16 + quad*4);

  // ---- build LUT via MFMA from f32 RE: lutT[p][q] = Qrel*ESCALE; p==0 -> -1e30 ----
  {
    const bf16* qbrow = Qp + (size_t)(b*SEQ + q0 + w*16 + l15)*EMBED + h*HD;
    bf16x8 ab0 = *(const bf16x8*)(qbrow + quad*8);
    bf16x8 ab1 = *(const bf16x8*)(qbrow + 32 + quad*8);
    #pragma unroll
    for (int nt = 0; nt < 3; ++nt){
      int p = nt*16 + l15;
      const int   pc = (p < NPOS) ? p : 0;
      const float fm = (p < NPOS) ? 1.f : 0.f;
      const float* rrow = RE + (size_t)pc*512 + h;   // RE[p][d*8+h]
      union { bf16 e[8]; bf16x8 v; } r0u, r1u;
      #pragma unroll
      for (int j = 0; j < 8; ++j){
        r0u.e[j] = (bf16)(fm * rrow[(quad*8 + j)*8]);
        r1u.e[j] = (bf16)(fm * rrow[(32 + quad*8 + j)*8]);
      }
      f32x4 c = (f32x4){0.f,0.f,0.f,0.f};
      c = mfma16(ab0, r0u.v, c);
      c = mfma16(ab1, r1u.v, c);
      if (p < NPOS){
        #pragma unroll
        for (int r = 0; r < 4; ++r)
          lutT[p][w*16 + quad*4 + r] = (p == 0) ? -1e30f : c[r];
      }
    }
  }

  // ---- QK B-frags (Q rows, reg-resident) ----
  bf16x8 bq[2][2];
  #pragma unroll
  for (int mt = 0; mt < 2; ++mt){
    const bf16* qrow = Qp + (size_t)(b*SEQ + q0 + qh*32 + mt*16 + l15)*EMBED + h*HD;
    bq[mt][0] = *(const bf16x8*)(qrow + quad*8);
    bq[mt][1] = *(const bf16x8*)(qrow + 32 + quad*8);
  }

  f32x4 acc[2][4];
  #pragma unroll
  for (int mt=0;mt<2;++mt)
    #pragma unroll
    for (int nt=0;nt<4;++nt) acc[mt][nt] = (f32x4){0.f,0.f,0.f,0.f};
  float lsum[2] = {0.f, 0.f};

#define ATTN_BODY(KT, K0,K1,K2,K3, V0,V1,V2,V3, L0,L1,L2,L3, M0,M1,M2,M3)       \
  {                                                                             \
    barrier_lgkm();  /* all waves done reading Ks/Vs of prev tile */            \
    *(uint4*)&Ks[krow     ][kcol] = K0;                                         \
    *(uint4*)&Ks[krow + 32][kcol] = K1;                                         \
    *(uint4*)&Ks[krow + 64][kcol] = K2;                                         \
    *(uint4*)&Ks[krow + 96][kcol] = K3;                                         \
    *(uint4*)&Vs[vrow     ][vcol] = V0;                                         \
    *(uint4*)&Vs[vrow + 16][vcol] = V1;                                         \
    *(uint4*)&Vs[vrow + 32][vcol] = V2;                                         \
    *(uint4*)&Vs[vrow + 48][vcol] = V3;                                         \
    if ((KT) < 15){                                                             \
      const bf16* kp2 = kbase + (size_t)(((KT)+1)*128)*EMBED + kcol;            \
      const bf16* vp2 = vbase + ((KT)+1)*128 + vcol;                            \
      L0 = *(const uint4*)(kp2 + (size_t)(krow     )*EMBED);                    \
      L1 = *(const uint4*)(kp2 + (size_t)(krow + 32)*EMBED);                    \
      L2 = *(const uint4*)(kp2 + (size_t)(krow + 64)*EMBED);                    \
      L3 = *(const uint4*)(kp2 + (size_t)(krow + 96)*EMBED);                    \
      M0 = *(const uint4*)(vp2 + (size_t)(vrow     )*SEQ);                      \
      M1 = *(const uint4*)(vp2 + (size_t)(vrow + 16)*SEQ);                      \
      M2 = *(const uint4*)(vp2 + (size_t)(vrow + 32)*SEQ);                      \
      M3 = *(const uint4*)(vp2 + (size_t)(vrow + 48)*SEQ);                      \
    }                                                                           \
    barrier_lgkm();  /* Ks/Vs ready; prefetch loads keep flying */              \
    float wvv[2][4][4];                                                         \
    _Pragma("unroll")                                                           \
    for (int mt = 0; mt < 2; ++mt){                                             \
      const float* lcol = &lutT[0][qh*32 + mt*16 + l15];                        \
      _Pragma("unroll")                                                         \
      for (int nt = 0; nt < 4; ++nt){                                           \
        int32x4 v = nid[mt][nt];                                                \
        wvv[mt][nt][0] = lcol[v[0] * 65];                                       \
        wvv[mt][nt][1] = lcol[v[1] * 65];                                       \
        wvv[mt][nt][2] = lcol[v[2] * 65];                                       \
        wvv[mt][nt][3] = lcol[v[3] * 65];                                       \
      }                                                                         \
    }                                                                           \
    if ((KT) < 15){                                                             \
      _Pragma("unroll")                                                         \
      for (int mt = 0; mt < 2; ++mt)                                            \
        _Pragma("unroll")                                                       \
        for (int nt = 0; nt < 4; ++nt)                                          \
          nid[mt][nt] = *(const int32x4*)(ids + idb                             \
              + (size_t)(q0 + qh*32 + mt*16 + l15)*SEQ                          \
              + (((KT)+1)*128) + kh*64 + nt*16 + quad*4);                       \
    }                                                                           \
    f32x4 sf[2][4];                                                             \
    __builtin_amdgcn_s_setprio(1);                                              \
    _Pragma("unroll")                                                           \
    for (int nt = 0; nt < 4; ++nt){                                             \
      bf16x8 ak0 = *(const bf16x8*)&Ks[kh*64 + nt*16 + l15][quad*8];            \
      bf16x8 ak1 = *(const bf16x8*)&Ks[kh*64 + nt*16 + l15][32 + quad*8];       \
      _Pragma("unroll")                                                         \
      for (int mt = 0; mt < 2; ++mt){                                           \
        f32x4 c = (f32x4){0.f,0.f,0.f,0.f};                                     \
        c = mfma16(ak0, bq[mt][0], c);                                          \
        c = mfma16(ak1, bq[mt][1], c);                                          \
        sf[mt][nt] = c;                                                         \
      }                                                                         \
    }                                                                           \
    __builtin_amdgcn_s_setprio(0);                                              \
    _Pragma("unroll")                                                           \
    for (int mt = 0; mt < 2; ++mt){                                             \
      _Pragma("unroll")                                                         \
      for (int nt = 0; nt < 4; ++nt){                                           \
        union { bf16 e[4]; uint2 u; } pk;                                       \
        float p0 = __builtin_amdgcn_exp2f(sf[mt][nt][0] + wvv[mt][nt][0]);      \
        float p1 = __builtin_amdgcn_exp2f(sf[mt][nt][1] + wvv[mt][nt][1]);      \
        float p2 = __builtin_amdgcn_exp2f(sf[mt][nt][2] + wvv[mt][nt][2]);      \
        float p3 = __builtin_amdgcn_exp2f(sf[mt][nt][3] + wvv[mt][nt][3]);      \
        pk.e[0] = (bf16)p0; pk.e[1] = (bf16)p1;                                 \
        pk.e[2] = (bf16)p2; pk.e[3] = (bf16)p3;                                 \
        lsum[mt] += (p0 + p1) + (p2 + p3);                                      \
        *(uint2*)&Ps[qh*32 + mt*16 + l15][kh*64 + nt*16 + quad*4] = pk.u;       \
      }                                                                         \
    }                                                                           \
    __builtin_amdgcn_s_setprio(1);                                              \
    _Pragma("unroll")                                                           \
    for (int ks = 0; ks < 2; ++ks){                                             \
      bf16x8 ap[2];                                                             \
      _Pragma("unroll")                                                         \
      for (int mt = 0; mt < 2; ++mt)                                            \
        ap[mt] = *(const bf16x8*)&Ps[qh*32 + mt*16 + l15][kh*64 + ks*32 + quad*8]; \
      _Pragma("unroll")                                                         \
      for (int nt = 0; nt < 4; ++nt){                                           \
        bf16x8 bv = *(const bf16x8*)&Vs[nt*16 + l15][kh*64 + ks*32 + quad*8];   \
        _Pragma("unroll")                                                       \
        for (int mt = 0; mt < 2; ++mt)                                          \
          acc[mt][nt] = mfma16(ap[mt], bv, acc[mt][nt]);                        \
      }                                                                         \
    }                                                                           \
    __builtin_amdgcn_s_setprio(0);                                              \
  }

  for (int kt2 = 0; kt2 < 16; kt2 += 2){
    ATTN_BODY(kt2,     ka0,ka1,ka2,ka3, va0,va1,va2,va3, kb0,kb1,kb2,kb3, vb0,vb1,vb2,vb3)
    ATTN_BODY(kt2 + 1, kb0,kb1,kb2,kb3, vb0,vb1,vb2,vb3, ka0,ka1,ka2,ka3, va0,va1,va2,va3)
  }
#undef ATTN_BODY

  // ---- epilogue (ALL acc indices compile-time; branches wave-uniform) ----
  __syncthreads();   // all waves done with Ks/Vs/Ps before Ps is overlaid

  // lsum: lane-local per q (own k-half); reduce over quad, publish per kh
  #pragma unroll
  for (int mt = 0; mt < 2; ++mt){
    float v = lsum[mt];
    v += __shfl_xor(v, 16);
    v += __shfl_xor(v, 32);
    if (quad == 0) lsum_s[kh*64 + qh*32 + mt*16 + l15] = v;
  }

  // kh==1 waves publish ALL partials; padded stride 65 -> conflict-free.
  float* xch = (float*)&Ps[0][0];   // 2*32*65*4 = 16640 B <= 17408
  if (kh == 1){
    #pragma unroll
    for (int mt = 0; mt < 2; ++mt)
      #pragma unroll
      for (int nt = 0; nt < 4; ++nt){
        f32x4 a = acc[mt][nt];
        #pragma unroll
        for (int r = 0; r < 4; ++r)
          xch[(qh*32 + mt*16 + quad*4 + r)*65 + nt*16 + l15] = a[r];
      }
  }
  __syncthreads();

  // kh==0 waves: add partner partials, normalize, store full 64-d row
  if (kh == 0){
    #pragma unroll
    for (int mt = 0; mt < 2; ++mt){
      #pragma unroll
      for (int r = 0; r < 4; ++r){
        int ql = qh*32 + mt*16 + quad*4 + r;
        float inv = __builtin_amdgcn_rcpf(lsum_s[ql] + lsum_s[64 + ql]);
        #pragma unroll
        for (int nt = 0; nt < 4; ++nt){
          float o = acc[mt][nt][r] + xch[ql*65 + nt*16 + l15];
          Out[(size_t)(b*SEQ + q0 + ql)*EMBED + h*HD + nt*16 + l15] = (bf16)(o*inv);
        }
      }
    }
  }
}

// ---------------- launch ----------------
extern "C" void kernel_launch(void* const* d_in, const int* in_sizes, int n_in,
                              void* d_out, int out_size, void* d_ws, size_t ws_size,
                              hipStream_t stream)
{
  (void)in_sizes; (void)n_in; (void)out_size;
  const float* Q  = (const float*)d_in[0];
  const float* K  = (const float*)d_in[1];
  const float* V  = (const float*)d_in[2];
  const int*   ID = (const int*)d_in[3];
  const float* Wq = (const float*)d_in[4];
  const float* Wk = (const float*)d_in[5];
  const float* Wv = (const float*)d_in[6];
  const float* Wo = (const float*)d_in[7];
  const float* RE = (const float*)d_in[8];
  float* out = (float*)d_out;

  const size_t MB = (size_t)1 << 20;
  if (ws_size < 36*MB) return;
  char* ws = (char*)d_ws;
  bf16*  AO    = (bf16*)(ws + 0*MB);             // 4 MB (attn out, bf16)
  bf16*  Qp    = (bf16*)(ws + 4*MB);             // 4 MB
  bf16*  Kp    = (bf16*)(ws + 8*MB);             // 4 MB
  bf16*  Vt    = (bf16*)(ws + 12*MB);            // 4 MB (b,h,d,s)
  bf16*  Wop   = (bf16*)(ws + 16*MB);            // 0.5 MB (Wo', col-permuted)

  k_proj      <<<dim3(8,32,4),  256, 0, stream>>>(Q, K, V, Wq, Wk, Wv, Wo,
                                                  Qp, Kp, Vt, Wop);
  k_attn      <<<dim3(32,8,2),  256, 0, stream>>>(Qp, Kp, Vt, RE, ID, AO);
  k_gemm_out  <<<dim3(8,32),    256, 0, stream>>>(AO, Wop, out);
}

// Round 7
// 179.590 us; speedup vs baseline: 2.1827x; 1.1235x over previous
//
#include <hip/hip_runtime.h>
#include <cstdint>
#include <cstddef>

#define SEQ   2048
#define BBAT  2
#define EMBED 512
#define NH    8
#define HD    64
#define NPOS  34

typedef __bf16 bf16;
typedef __bf16 bf16x8 __attribute__((ext_vector_type(8)));
typedef float  f32x4  __attribute__((ext_vector_type(4)));
typedef int    int32x4 __attribute__((ext_vector_type(4)));

// scale = log2(e)/8 : energy=(qk+bias)/8, computed in exp2 domain.
// ESCALE is folded into Qp at the projection epilogue (z==0).
#define ESCALE 0.1803368801111204f

__device__ __forceinline__ f32x4 mfma16(bf16x8 a, bf16x8 b, f32x4 c){
  return __builtin_amdgcn_mfma_f32_16x16x32_bf16(a, b, c, 0, 0, 0);
}

// lgkm-only barrier: does NOT drain vmcnt, so prefetch global loads stay in
// flight across it. sched_barrier(0) pins LDS ops on the correct side.
__device__ __forceinline__ void barrier_lgkm(){
  asm volatile("s_waitcnt lgkmcnt(0)" ::: "memory");
  __builtin_amdgcn_s_barrier();
  __builtin_amdgcn_sched_barrier(0);
}

// ---------------- kernel 1: fused prep (verbatim R4) ----------------
__global__ __launch_bounds__(256) void k_prep(
    const float* __restrict__ Q, const float* __restrict__ K, const float* __restrict__ V,
    const float* __restrict__ Wq, const float* __restrict__ Wk,
    const float* __restrict__ Wv, const float* __restrict__ Wo,
    const float* __restrict__ RE,
    bf16* __restrict__ Qb, bf16* __restrict__ Kb, bf16* __restrict__ Vb,
    bf16* __restrict__ Wall, bf16* __restrict__ Rb)
{
  const int NCONV = 3*524288;
  const int NW = 196608, NO = 262144;
  int i = blockIdx.x*256 + threadIdx.x;
  if (i < NCONV){
    int tsel = i >> 19, j = i & 524287;
    const float* s = tsel==0 ? Q : (tsel==1 ? K : V);
    bf16* d       = tsel==0 ? Qb : (tsel==1 ? Kb : Vb);
    float4 v = ((const float4*)s)[j];
    union { bf16 e[4]; ushort4 u; } pk;
    pk.e[0]=(bf16)v.x; pk.e[1]=(bf16)v.y; pk.e[2]=(bf16)v.z; pk.e[3]=(bf16)v.w;
    ((ushort4*)d)[j] = pk.u;
  } else {
    int j = i - NCONV;
    if (j < NW){
      int w  = j >> 16;
      int r  = j & 65535;
      int np = r >> 7, c4 = (r & 127) << 2;
      const float* W = (w==0) ? Wq : ((w==1) ? Wk : Wv);
      int src = ((np & 63) << 3) + (np >> 6);
      float4 v = *(const float4*)(W + (size_t)src*512 + c4);
      union { bf16 e[4]; ushort4 u; } pk;
      pk.e[0]=(bf16)v.x; pk.e[1]=(bf16)v.y; pk.e[2]=(bf16)v.z; pk.e[3]=(bf16)v.w;
      *(ushort4*)(Wall + (size_t)w*262144 + (size_t)np*512 + c4) = pk.u;
    } else if (j < NW + NO){
      int jj = j - NW;
      int n = jj >> 9, kp = jj & 511;
      int src = ((kp & 63) << 3) + (kp >> 6);
      Wall[(size_t)3*262144 + (size_t)n*512 + kp] = (bf16)Wo[(size_t)n*512 + src];
    } else {
      int jj = j - NW - NO;
      if (jj < 8*48*64){
        int h  = jj / (48*64);
        int r2 = jj - h*(48*64);
        int p  = r2 >> 6, dd = r2 & 63;
        float v = (p < NPOS) ? RE[(size_t)p*512 + dd*8 + h] : 0.f;
        Rb[jj] = (bf16)v;
      }
    }
  }
}

// ---------------- kernel 2: projections, 128x128 tile, reg-dbuf pipelined ----------------
// R6 analysis: old 128x64 proj ran ~40-50us (16 MFMA/wave/k-step against full
// staging + 2 vmcnt-drain barriers). This version: 128x128 tile (32 MFMA/wave/
// k-step), attn-style named-register double-buffer of the next k-tile + lgkm-
// only barriers so global loads fly across the whole compute phase.
// z==0 folds ESCALE into Qp; z==2 writes V transposed (b,h,d,s).
__global__ __launch_bounds__(256,2) void k_proj(
    const bf16* __restrict__ Qb, const bf16* __restrict__ Kb, const bf16* __restrict__ Vb,
    const bf16* __restrict__ W,
    bf16* __restrict__ Qp, bf16* __restrict__ Kp, bf16* __restrict__ Vt)
{
  const int z = blockIdx.z;
  const bf16* A  = z==0 ? Qb : (z==1 ? Kb : Vb);
  const bf16* Bw = W + (size_t)z*262144;

  __shared__ __align__(16) bf16 AB[2][128][72];   // 36864 B -> 2 WG/CU
  bf16 (*As)[72] = AB[0];
  bf16 (*Bs)[72] = AB[1];

  const int t = threadIdx.x;
  const int w = t >> 6, lane = t & 63, l15 = lane & 15, quad = lane >> 4;
  const int wm = (w & 1) * 64, wn = (w >> 1) * 64;
  const int m0 = blockIdx.y * 128, n0 = blockIdx.x * 128;
  const int row = t >> 3, c8 = (t & 7) << 3;

  const bf16* Abase = A  + (size_t)(m0 + row)*512 + c8;
  const bf16* Bbase = Bw + (size_t)(n0 + row)*512 + c8;

  uint4 pa0,pa1,pa2,pa3, pb0,pb1,pb2,pb3;
  uint4 qa0,qa1,qa2,qa3, qb0,qb1,qb2,qb3;
  pa0 = *(const uint4*)(Abase);
  pa1 = *(const uint4*)(Abase + 32*512);
  pa2 = *(const uint4*)(Abase + 64*512);
  pa3 = *(const uint4*)(Abase + 96*512);
  pb0 = *(const uint4*)(Bbase);
  pb1 = *(const uint4*)(Bbase + 32*512);
  pb2 = *(const uint4*)(Bbase + 64*512);
  pb3 = *(const uint4*)(Bbase + 96*512);

  f32x4 acc[4][4];
  #pragma unroll
  for (int mt=0; mt<4; ++mt)
    #pragma unroll
    for (int nt=0; nt<4; ++nt) acc[mt][nt] = (f32x4){0.f,0.f,0.f,0.f};

#define PROJ_BODY(KT, A0,A1,A2,A3, B0,B1,B2,B3, LA0,LA1,LA2,LA3, LB0,LB1,LB2,LB3) \
  {                                                                             \
    barrier_lgkm();  /* all waves done reading prev tile */                     \
    *(uint4*)&As[row     ][c8] = A0;                                            \
    *(uint4*)&As[row + 32][c8] = A1;                                            \
    *(uint4*)&As[row + 64][c8] = A2;                                            \
    *(uint4*)&As[row + 96][c8] = A3;                                            \
    *(uint4*)&Bs[row     ][c8] = B0;                                            \
    *(uint4*)&Bs[row + 32][c8] = B1;                                            \
    *(uint4*)&Bs[row + 64][c8] = B2;                                            \
    *(uint4*)&Bs[row + 96][c8] = B3;                                            \
    if ((KT) < 7){                                                              \
      const bf16* ap2 = Abase + ((KT)+1)*64;                                    \
      const bf16* bp2 = Bbase + ((KT)+1)*64;                                    \
      LA0 = *(const uint4*)(ap2);                                               \
      LA1 = *(const uint4*)(ap2 + 32*512);                                      \
      LA2 = *(const uint4*)(ap2 + 64*512);                                      \
      LA3 = *(const uint4*)(ap2 + 96*512);                                      \
      LB0 = *(const uint4*)(bp2);                                               \
      LB1 = *(const uint4*)(bp2 + 32*512);                                      \
      LB2 = *(const uint4*)(bp2 + 64*512);                                      \
      LB3 = *(const uint4*)(bp2 + 96*512);                                      \
    }                                                                           \
    barrier_lgkm();  /* LDS ready; prefetch loads keep flying */                \
    __builtin_amdgcn_s_setprio(1);                                              \
    _Pragma("unroll")                                                           \
    for (int ks = 0; ks < 2; ++ks){                                             \
      bf16x8 am[4], bn[4];                                                      \
      _Pragma("unroll")                                                         \
      for (int x=0;x<4;++x) am[x] = *(const bf16x8*)&As[wm + x*16 + l15][ks*32 + quad*8]; \
      _Pragma("unroll")                                                         \
      for (int y=0;y<4;++y) bn[y] = *(const bf16x8*)&Bs[wn + y*16 + l15][ks*32 + quad*8]; \
      _Pragma("unroll")                                                         \
      for (int mt=0;mt<4;++mt)                                                  \
        _Pragma("unroll")                                                       \
        for (int nt=0;nt<4;++nt)                                                \
          acc[mt][nt] = mfma16(am[mt], bn[nt], acc[mt][nt]);                    \
    }                                                                           \
    __builtin_amdgcn_s_setprio(0);                                              \
  }

  for (int kt2 = 0; kt2 < 8; kt2 += 2){
    PROJ_BODY(kt2,     pa0,pa1,pa2,pa3, pb0,pb1,pb2,pb3, qa0,qa1,qa2,qa3, qb0,qb1,qb2,qb3)
    PROJ_BODY(kt2 + 1, qa0,qa1,qa2,qa3, qb0,qb1,qb2,qb3, pa0,pa1,pa2,pa3, pb0,pb1,pb2,pb3)
  }
#undef PROJ_BODY

  if (z != 2){
    bf16* C = z==0 ? Qp : Kp;
    const float scl = (z==0) ? ESCALE : 1.0f;
    #pragma unroll
    for (int mt=0;mt<4;++mt)
      #pragma unroll
      for (int r=0;r<4;++r){
        int m = m0 + wm + mt*16 + quad*4 + r;
        #pragma unroll
        for (int nt=0;nt<4;++nt)
          C[(size_t)m*512 + n0 + wn + nt*16 + l15] = (bf16)(acc[mt][nt][r] * scl);
      }
  } else {
    // V: transpose in-LDS (overlay on As+Bs), coalesced store to Vt (b,h,d,s)
    __syncthreads();
    bf16 (*VT)[136] = (bf16(*)[136])AB;    // 128 x 136 x 2 = 34816 <= 36864
    #pragma unroll
    for (int mt=0;mt<4;++mt)
      #pragma unroll
      for (int r=0;r<4;++r){
        int m = wm + mt*16 + quad*4 + r;
        #pragma unroll
        for (int nt=0;nt<4;++nt)
          VT[wn + nt*16 + l15][m] = (bf16)acc[mt][nt][r];
      }
    __syncthreads();
    const int b = m0 >> 11, s0 = m0 & 2047;
    const int n = t >> 1, c0 = (t & 1) * 64;    // n: 0..127 = (h_lo, d)
    const int h = blockIdx.x*2 + (n >> 6), d = n & 63;
    bf16* dst = Vt + ((size_t)((b*NH + h)*HD + d))*SEQ + s0 + c0;
    #pragma unroll
    for (int i = 0; i < 8; ++i)
      *(uint4*)(dst + i*8) = *(const uint4*)&VT[n][c0 + i*8];
  }
}

// ---------------- kernel 4: output projection, 128x128 tile, same pipeline ----------------
__global__ __launch_bounds__(256,2) void k_gemm_out(
    const bf16* __restrict__ A, const bf16* __restrict__ Bw, float* __restrict__ C)
{
  __shared__ __align__(16) bf16 AB[2][128][72];
  bf16 (*As)[72] = AB[0];
  bf16 (*Bs)[72] = AB[1];

  const int t = threadIdx.x;
  const int w = t >> 6, lane = t & 63, l15 = lane & 15, quad = lane >> 4;
  const int wm = (w & 1) * 64, wn = (w >> 1) * 64;
  const int m0 = blockIdx.y * 128, n0 = blockIdx.x * 128;
  const int row = t >> 3, c8 = (t & 7) << 3;

  const bf16* Abase = A  + (size_t)(m0 + row)*512 + c8;
  const bf16* Bbase = Bw + (size_t)(n0 + row)*512 + c8;

  uint4 pa0,pa1,pa2,pa3, pb0,pb1,pb2,pb3;
  uint4 qa0,qa1,qa2,qa3, qb0,qb1,qb2,qb3;
  pa0 = *(const uint4*)(Abase);
  pa1 = *(const uint4*)(Abase + 32*512);
  pa2 = *(const uint4*)(Abase + 64*512);
  pa3 = *(const uint4*)(Abase + 96*512);
  pb0 = *(const uint4*)(Bbase);
  pb1 = *(const uint4*)(Bbase + 32*512);
  pb2 = *(const uint4*)(Bbase + 64*512);
  pb3 = *(const uint4*)(Bbase + 96*512);

  f32x4 acc[4][4];
  #pragma unroll
  for (int mt=0; mt<4; ++mt)
    #pragma unroll
    for (int nt=0; nt<4; ++nt) acc[mt][nt] = (f32x4){0.f,0.f,0.f,0.f};

#define OUT_BODY(KT, A0,A1,A2,A3, B0,B1,B2,B3, LA0,LA1,LA2,LA3, LB0,LB1,LB2,LB3) \
  {                                                                             \
    barrier_lgkm();                                                             \
    *(uint4*)&As[row     ][c8] = A0;                                            \
    *(uint4*)&As[row + 32][c8] = A1;                                            \
    *(uint4*)&As[row + 64][c8] = A2;                                            \
    *(uint4*)&As[row + 96][c8] = A3;                                            \
    *(uint4*)&Bs[row     ][c8] = B0;                                            \
    *(uint4*)&Bs[row + 32][c8] = B1;                                            \
    *(uint4*)&Bs[row + 64][c8] = B2;                                            \
    *(uint4*)&Bs[row + 96][c8] = B3;                                            \
    if ((KT) < 7){                                                              \
      const bf16* ap2 = Abase + ((KT)+1)*64;                                    \
      const bf16* bp2 = Bbase + ((KT)+1)*64;                                    \
      LA0 = *(const uint4*)(ap2);                                               \
      LA1 = *(const uint4*)(ap2 + 32*512);                                      \
      LA2 = *(const uint4*)(ap2 + 64*512);                                      \
      LA3 = *(const uint4*)(ap2 + 96*512);                                      \
      LB0 = *(const uint4*)(bp2);                                               \
      LB1 = *(const uint4*)(bp2 + 32*512);                                      \
      LB2 = *(const uint4*)(bp2 + 64*512);                                      \
      LB3 = *(const uint4*)(bp2 + 96*512);                                      \
    }                                                                           \
    barrier_lgkm();                                                             \
    __builtin_amdgcn_s_setprio(1);                                              \
    _Pragma("unroll")                                                           \
    for (int ks = 0; ks < 2; ++ks){                                             \
      bf16x8 am[4], bn[4];                                                      \
      _Pragma("unroll")                                                         \
      for (int x=0;x<4;++x) am[x] = *(const bf16x8*)&As[wm + x*16 + l15][ks*32 + quad*8]; \
      _Pragma("unroll")                                                         \
      for (int y=0;y<4;++y) bn[y] = *(const bf16x8*)&Bs[wn + y*16 + l15][ks*32 + quad*8]; \
      _Pragma("unroll")                                                         \
      for (int mt=0;mt<4;++mt)                                                  \
        _Pragma("unroll")                                                       \
        for (int nt=0;nt<4;++nt)                                                \
          acc[mt][nt] = mfma16(am[mt], bn[nt], acc[mt][nt]);                    \
    }                                                                           \
    __builtin_amdgcn_s_setprio(0);                                              \
  }

  for (int kt2 = 0; kt2 < 8; kt2 += 2){
    OUT_BODY(kt2,     pa0,pa1,pa2,pa3, pb0,pb1,pb2,pb3, qa0,qa1,qa2,qa3, qb0,qb1,qb2,qb3)
    OUT_BODY(kt2 + 1, qa0,qa1,qa2,qa3, qb0,qb1,qb2,qb3, pa0,pa1,pa2,pa3, pb0,pb1,pb2,pb3)
  }
#undef OUT_BODY

  #pragma unroll
  for (int mt=0;mt<4;++mt)
    #pragma unroll
    for (int r=0;r<4;++r){
      int m = m0 + wm + mt*16 + quad*4 + r;
      #pragma unroll
      for (int nt=0;nt<4;++nt)
        C[(size_t)m*512 + n0 + wn + nt*16 + l15] = acc[mt][nt][r];
    }
}

// ---------------- kernel 3: flash attention (verbatim R4 v5, 58.9us verified) ----------------
__global__ __launch_bounds__(256,2) void k_attn(
    const bf16* __restrict__ Qp, const bf16* __restrict__ Kp,
    const bf16* __restrict__ Vt, const bf16* __restrict__ Rb,
    const int* __restrict__ ids, bf16* __restrict__ Out)
{
  // LDS: 18432 + 17408 + 17408 + 9100 + 512 = 62860 B -> 2 WG/CU
  __shared__ __align__(16) bf16 Ks[128][72];
  __shared__ __align__(16) bf16 Vs[64][136];
  __shared__ __align__(16) bf16 Ps[64][136];
  __shared__ float lutT[35][65];
  __shared__ float lsum_s[128];

  const int t = threadIdx.x;
  const int b = blockIdx.z, h = blockIdx.y;
  const int q0 = blockIdx.x * 64;
  const int w = t >> 6, lane = t & 63, l15 = lane & 15, quad = lane >> 4;
  const int qh = w & 1, kh = w >> 1;

  const size_t idb = (size_t)b*SEQ*SEQ;
  const bf16* kbase = Kp + (size_t)b*SEQ*EMBED + h*HD;
  const bf16* vbase = Vt + (size_t)(b*NH + h)*HD*SEQ;

  const int krow = t >> 3, kcol = (t & 7) << 3;
  const int vrow = t >> 4, vcol = (t & 15) << 3;

  uint4 ka0, ka1, ka2, ka3, va0, va1, va2, va3;
  uint4 kb0, kb1, kb2, kb3, vb0, vb1, vb2, vb3;
  ka0 = *(const uint4*)(kbase + (size_t)(krow     )*EMBED + kcol);
  ka1 = *(const uint4*)(kbase + (size_t)(krow + 32)*EMBED + kcol);
  ka2 = *(const uint4*)(kbase + (size_t)(krow + 64)*EMBED + kcol);
  ka3 = *(const uint4*)(kbase + (size_t)(krow + 96)*EMBED + kcol);
  va0 = *(const uint4*)(vbase + (size_t)(vrow     )*SEQ + vcol);
  va1 = *(const uint4*)(vbase + (size_t)(vrow + 16)*SEQ + vcol);
  va2 = *(const uint4*)(vbase + (size_t)(vrow + 32)*SEQ + vcol);
  va3 = *(const uint4*)(vbase + (size_t)(vrow + 48)*SEQ + vcol);

  int32x4 nid[2][4];
  #pragma unroll
  for (int mt=0; mt<2; ++mt)
    #pragma unroll
    for (int nt=0; nt<4; ++nt)
      nid[mt][nt] = *(const int32x4*)(ids + idb
          + (size_t)(q0 + qh*32 + mt*16 + l15)*SEQ
          + kh*64 + nt*16 + quad*4);

  {
    const bf16* qbrow = Qp + (size_t)(b*SEQ + q0 + w*16 + l15)*EMBED + h*HD;
    bf16x8 ab0 = *(const bf16x8*)(qbrow + quad*8);
    bf16x8 ab1 = *(const bf16x8*)(qbrow + 32 + quad*8);
    const bf16* rh = Rb + h*3072;
    #pragma unroll
    for (int nt = 0; nt < 3; ++nt){
      bf16x8 r0 = *(const bf16x8*)(rh + (nt*16 + l15)*64 + quad*8);
      bf16x8 r1 = *(const bf16x8*)(rh + (nt*16 + l15)*64 + 32 + quad*8);
      f32x4 c = (f32x4){0.f,0.f,0.f,0.f};
      c = mfma16(ab0, r0, c);
      c = mfma16(ab1, r1, c);
      int p = nt*16 + l15;
      if (p < NPOS){
        #pragma unroll
        for (int r = 0; r < 4; ++r)
          lutT[p][w*16 + quad*4 + r] = (p == 0) ? -1e30f : c[r];
      }
    }
  }

  bf16x8 bq[2][2];
  #pragma unroll
  for (int mt = 0; mt < 2; ++mt){
    const bf16* qrow = Qp + (size_t)(b*SEQ + q0 + qh*32 + mt*16 + l15)*EMBED + h*HD;
    bq[mt][0] = *(const bf16x8*)(qrow + quad*8);
    bq[mt][1] = *(const bf16x8*)(qrow + 32 + quad*8);
  }

  f32x4 acc[2][4];
  #pragma unroll
  for (int mt=0;mt<2;++mt)
    #pragma unroll
    for (int nt=0;nt<4;++nt) acc[mt][nt] = (f32x4){0.f,0.f,0.f,0.f};
  float lsum[2] = {0.f, 0.f};

#define ATTN_BODY(KT, K0,K1,K2,K3, V0,V1,V2,V3, L0,L1,L2,L3, M0,M1,M2,M3)       \
  {                                                                             \
    barrier_lgkm();  /* all waves done reading Ks/Vs of prev tile */            \
    *(uint4*)&Ks[krow     ][kcol] = K0;                                         \
    *(uint4*)&Ks[krow + 32][kcol] = K1;                                         \
    *(uint4*)&Ks[krow + 64][kcol] = K2;                                         \
    *(uint4*)&Ks[krow + 96][kcol] = K3;                                         \
    *(uint4*)&Vs[vrow     ][vcol] = V0;                                         \
    *(uint4*)&Vs[vrow + 16][vcol] = V1;                                         \
    *(uint4*)&Vs[vrow + 32][vcol] = V2;                                         \
    *(uint4*)&Vs[vrow + 48][vcol] = V3;                                         \
    if ((KT) < 15){                                                             \
      const bf16* kp2 = kbase + (size_t)(((KT)+1)*128)*EMBED + kcol;            \
      const bf16* vp2 = vbase + ((KT)+1)*128 + vcol;                            \
      L0 = *(const uint4*)(kp2 + (size_t)(krow     )*EMBED);                    \
      L1 = *(const uint4*)(kp2 + (size_t)(krow + 32)*EMBED);                    \
      L2 = *(const uint4*)(kp2 + (size_t)(krow + 64)*EMBED);                    \
      L3 = *(const uint4*)(kp2 + (size_t)(krow + 96)*EMBED);                    \
      M0 = *(const uint4*)(vp2 + (size_t)(vrow     )*SEQ);                      \
      M1 = *(const uint4*)(vp2 + (size_t)(vrow + 16)*SEQ);                      \
      M2 = *(const uint4*)(vp2 + (size_t)(vrow + 32)*SEQ);                      \
      M3 = *(const uint4*)(vp2 + (size_t)(vrow + 48)*SEQ);                      \
    }                                                                           \
    barrier_lgkm();  /* Ks/Vs ready; prefetch loads keep flying */              \
    float wvv[2][4][4];                                                         \
    _Pragma("unroll")                                                           \
    for (int mt = 0; mt < 2; ++mt){                                             \
      const float* lcol = &lutT[0][qh*32 + mt*16 + l15];                        \
      _Pragma("unroll")                                                         \
      for (int nt = 0; nt < 4; ++nt){                                           \
        int32x4 v = nid[mt][nt];                                                \
        wvv[mt][nt][0] = lcol[v[0] * 65];                                       \
        wvv[mt][nt][1] = lcol[v[1] * 65];                                       \
        wvv[mt][nt][2] = lcol[v[2] * 65];                                       \
        wvv[mt][nt][3] = lcol[v[3] * 65];                                       \
      }                                                                         \
    }                                                                           \
    if ((KT) < 15){                                                             \
      _Pragma("unroll")                                                         \
      for (int mt = 0; mt < 2; ++mt)                                            \
        _Pragma("unroll")                                                       \
        for (int nt = 0; nt < 4; ++nt)                                          \
          nid[mt][nt] = *(const int32x4*)(ids + idb                             \
              + (size_t)(q0 + qh*32 + mt*16 + l15)*SEQ                          \
              + (((KT)+1)*128) + kh*64 + nt*16 + quad*4);                       \
    }                                                                           \
    f32x4 sf[2][4];                                                             \
    __builtin_amdgcn_s_setprio(1);                                              \
    _Pragma("unroll")                                                           \
    for (int nt = 0; nt < 4; ++nt){                                             \
      bf16x8 ak0 = *(const bf16x8*)&Ks[kh*64 + nt*16 + l15][quad*8];            \
      bf16x8 ak1 = *(const bf16x8*)&Ks[kh*64 + nt*16 + l15][32 + quad*8];       \
      _Pragma("unroll")                                                         \
      for (int mt = 0; mt < 2; ++mt){                                           \
        f32x4 c = (f32x4){0.f,0.f,0.f,0.f};                                     \
        c = mfma16(ak0, bq[mt][0], c);                                          \
        c = mfma16(ak1, bq[mt][1], c);                                          \
        sf[mt][nt] = c;                                                         \
      }                                                                         \
    }                                                                           \
    __builtin_amdgcn_s_setprio(0);                                              \
    _Pragma("unroll")                                                           \
    for (int mt = 0; mt < 2; ++mt){                                             \
      _Pragma("unroll")                                                         \
      for (int nt = 0; nt < 4; ++nt){                                           \
        union { bf16 e[4]; uint2 u; } pk;                                       \
        float p0 = __builtin_amdgcn_exp2f(sf[mt][nt][0] + wvv[mt][nt][0]);      \
        float p1 = __builtin_amdgcn_exp2f(sf[mt][nt][1] + wvv[mt][nt][1]);      \
        float p2 = __builtin_amdgcn_exp2f(sf[mt][nt][2] + wvv[mt][nt][2]);      \
        float p3 = __builtin_amdgcn_exp2f(sf[mt][nt][3] + wvv[mt][nt][3]);      \
        pk.e[0] = (bf16)p0; pk.e[1] = (bf16)p1;                                 \
        pk.e[2] = (bf16)p2; pk.e[3] = (bf16)p3;                                 \
        lsum[mt] += (p0 + p1) + (p2 + p3);                                      \
        *(uint2*)&Ps[qh*32 + mt*16 + l15][kh*64 + nt*16 + quad*4] = pk.u;       \
      }                                                                         \
    }                                                                           \
    __builtin_amdgcn_s_setprio(1);                                              \
    _Pragma("unroll")                                                           \
    for (int ks = 0; ks < 2; ++ks){                                             \
      bf16x8 ap[2];                                                             \
      _Pragma("unroll")                                                         \
      for (int mt = 0; mt < 2; ++mt)                                            \
        ap[mt] = *(const bf16x8*)&Ps[qh*32 + mt*16 + l15][kh*64 + ks*32 + quad*8]; \
      _Pragma("unroll")                                                         \
      for (int nt = 0; nt < 4; ++nt){                                           \
        bf16x8 bv = *(const bf16x8*)&Vs[nt*16 + l15][kh*64 + ks*32 + quad*8];   \
        _Pragma("unroll")                                                       \
        for (int mt = 0; mt < 2; ++mt)                                          \
          acc[mt][nt] = mfma16(ap[mt], bv, acc[mt][nt]);                        \
      }                                                                         \
    }                                                                           \
    __builtin_amdgcn_s_setprio(0);                                              \
  }

  for (int kt2 = 0; kt2 < 16; kt2 += 2){
    ATTN_BODY(kt2,     ka0,ka1,ka2,ka3, va0,va1,va2,va3, kb0,kb1,kb2,kb3, vb0,vb1,vb2,vb3)
    ATTN_BODY(kt2 + 1, kb0,kb1,kb2,kb3, vb0,vb1,vb2,vb3, ka0,ka1,ka2,ka3, va0,va1,va2,va3)
  }
#undef ATTN_BODY

  // ---- epilogue (ALL acc indices compile-time; branches wave-uniform) ----
  __syncthreads();

  #pragma unroll
  for (int mt = 0; mt < 2; ++mt){
    float v = lsum[mt];
    v += __shfl_xor(v, 16);
    v += __shfl_xor(v, 32);
    if (quad == 0) lsum_s[kh*64 + qh*32 + mt*16 + l15] = v;
  }

  float* xch = (float*)&Ps[0][0];   // 2*32*65*4 = 16640 B <= 17408
  if (kh == 1){
    #pragma unroll
    for (int mt = 0; mt < 2; ++mt)
      #pragma unroll
      for (int nt = 0; nt < 4; ++nt){
        f32x4 a = acc[mt][nt];
        #pragma unroll
        for (int r = 0; r < 4; ++r)
          xch[(qh*32 + mt*16 + quad*4 + r)*65 + nt*16 + l15] = a[r];
      }
  }
  __syncthreads();

  if (kh == 0){
    #pragma unroll
    for (int mt = 0; mt < 2; ++mt){
      #pragma unroll
      for (int r = 0; r < 4; ++r){
        int ql = qh*32 + mt*16 + quad*4 + r;
        float inv = __builtin_amdgcn_rcpf(lsum_s[ql] + lsum_s[64 + ql]);
        #pragma unroll
        for (int nt = 0; nt < 4; ++nt){
          float o = acc[mt][nt][r] + xch[ql*65 + nt*16 + l15];
          Out[(size_t)(b*SEQ + q0 + ql)*EMBED + h*HD + nt*16 + l15] = (bf16)(o*inv);
        }
      }
    }
  }
}

// ---------------- launch ----------------
extern "C" void kernel_launch(void* const* d_in, const int* in_sizes, int n_in,
                              void* d_out, int out_size, void* d_ws, size_t ws_size,
                              hipStream_t stream)
{
  (void)in_sizes; (void)n_in; (void)out_size;
  const float* Q  = (const float*)d_in[0];
  const float* K  = (const float*)d_in[1];
  const float* V  = (const float*)d_in[2];
  const int*   ID = (const int*)d_in[3];
  const float* Wq = (const float*)d_in[4];
  const float* Wk = (const float*)d_in[5];
  const float* Wv = (const float*)d_in[6];
  const float* Wo = (const float*)d_in[7];
  const float* RE = (const float*)d_in[8];
  float* out = (float*)d_out;

  const size_t MB = (size_t)1 << 20;
  if (ws_size < 36*MB) return;
  char* ws = (char*)d_ws;
  bf16*  Qb    = (bf16*)(ws + 0*MB);             // dead after proj -> AO overlay
  bf16*  Kb    = (bf16*)(ws + 4*MB);
  bf16*  Vb    = (bf16*)(ws + 8*MB);
  bf16*  Qp    = (bf16*)(ws + 12*MB);
  bf16*  Kp    = (bf16*)(ws + 16*MB);
  bf16*  Vt    = (bf16*)(ws + 20*MB);            // (b,h,d,s) written by proj z==2
  bf16*  Wall  = (bf16*)(ws + 24*MB);            // 2 MB (Wq',Wk',Wv',Wo')
  bf16*  Wop   = Wall + (size_t)3*262144;
  bf16*  Rb    = (bf16*)(ws + 26*MB);            // 48 KB
  bf16*  AO    = (bf16*)(ws + 0*MB);             // overlays Qb

  k_prep      <<<dim3(8032),    256, 0, stream>>>(Q, K, V, Wq, Wk, Wv, Wo, RE,
                                                  Qb, Kb, Vb, Wall, Rb);
  k_proj      <<<dim3(4,32,3),  256, 0, stream>>>(Qb, Kb, Vb, Wall, Qp, Kp, Vt);
  k_attn      <<<dim3(32,8,2),  256, 0, stream>>>(Qp, Kp, Vt, Rb, ID, AO);
  k_gemm_out  <<<dim3(4,32),    256, 0, stream>>>(AO, Wop, out);
}